// Round 15
// baseline (420.482 us; speedup 1.0000x reference)
//
#include <hip/hip_runtime.h>
#include <hip/hip_bf16.h>
#include <stdint.h>
#include <math.h>

// B=4, N=1024, D=1024, H=8, DK=128, L=512. All internal tensors bf16 in ws.
// GEMM convention everywhere: C[m,n] = sum_k A[m,k]*B[n,k]  (B stored [N,K]).

typedef __attribute__((ext_vector_type(8))) __bf16 bf16x8;
typedef __attribute__((ext_vector_type(4))) float f32x4;

#define DEV static __device__ __forceinline__

DEV float bf2f(unsigned short u){ union { unsigned int i; float f; } x; x.i = ((unsigned int)u) << 16; return x.f; }
DEV unsigned short f2bf(float f){ union { float f; unsigned int i; } x; x.f = f;
  unsigned int r = x.i + 0x7FFFu + ((x.i >> 16) & 1u); return (unsigned short)(r >> 16); }

#define GLDS16(gp, lp) __builtin_amdgcn_global_load_lds( \
    (const __attribute__((address_space(1))) void*)(gp), \
    (__attribute__((address_space(3))) void*)(lp), 16, 0, 0)

// ---------------- merged f32 -> bf16 convert: query,key,value,rel_emb + bias pack ----------------
__global__ __launch_bounds__(256) void k_convert4(const float* __restrict__ q,
    const float* __restrict__ k, const float* __restrict__ v,
    const float* __restrict__ r, ushort4* __restrict__ dst,
    const float* __restrict__ bq, const float* __restrict__ bk,
    const float* __restrict__ bv, float* __restrict__ biasPack){
  const int total = 3407872;   // 3*1048576 + 262144 float4 groups
  int gid = blockIdx.x * blockDim.x + threadIdx.x;
  if (gid < 3072)
    biasPack[gid] = (gid < 1024) ? bq[gid] : (gid < 2048 ? bk[gid - 1024] : bv[gid - 2048]);
  for (int i = gid; i < total; i += gridDim.x * blockDim.x){
    const float4* s;
    if (i < 2097152) s = (i < 1048576) ? ((const float4*)q + i) : ((const float4*)k + (i - 1048576));
    else             s = (i < 3145728) ? ((const float4*)v + (i - 2097152)) : ((const float4*)r + (i - 3145728));
    float4 x = *s;
    ushort4 o; o.x = f2bf(x.x); o.y = f2bf(x.y); o.z = f2bf(x.z); o.w = f2bf(x.w);
    dst[i] = o;
  }
}

// ---------------- merged weight transpose: 8 weights, W [1024,N] f32 -> WT [N,1024] bf16 ----
struct WtArgs { const float* W[8]; unsigned short* Wd[8]; int N[8]; };
__global__ __launch_bounds__(256) void k_wtrans8(WtArgs a){
  __shared__ unsigned short t[64][65];
  const int z = blockIdx.z, N = a.N[z];
  const int n0 = blockIdx.x * 64, k0 = blockIdx.y * 64;
  if (n0 >= N) return;
  const float* W = a.W[z];
  unsigned short* WT = a.Wd[z];
  int tx = threadIdx.x, ty = threadIdx.y;
  for (int r = ty; r < 64; r += 4) t[r][tx] = f2bf(W[(long)(k0 + r) * N + n0 + tx]);
  __syncthreads();
  for (int r = ty; r < 64; r += 4) WT[(long)(n0 + r) * 1024 + k0 + tx] = t[tx][r];
}

// ---------------- v [z][1024][128] -> vT [z][128][1024] (bf16) ----------------
__global__ __launch_bounds__(256) void k_vtrans(const unsigned short* __restrict__ V,
                                                unsigned short* __restrict__ VT){
  __shared__ unsigned short t[64][65];
  int z = blockIdx.z, d0 = blockIdx.x * 64, j0 = blockIdx.y * 64;
  int tx = threadIdx.x, ty = threadIdx.y;
  const unsigned short* v = V + (long)z * 131072;
  unsigned short* vt = VT + (long)z * 131072;
  for (int r = ty; r < 64; r += 4) t[r][tx] = v[(j0 + r) * 128 + d0 + tx];
  __syncthreads();
  for (int r = ty; r < 64; r += 4) vt[(d0 + r) * 1024 + j0 + tx] = t[tx][r];
}

// ---------------- GEMM: 128x128 tile, BK=32, 4 waves (2x2), m97 structure ----------------
// MODE 0: plain bf16 out [z][M][N]                       (tables)
// MODE 6: merged q/k/v projection: M=12288, B segment by m0>>12, packed bias,
//         scale only on segment 0, head-split remap into contiguous qs|kk|vv
template<int MODE>
__global__ __launch_bounds__(256) void k_gemm(
    const unsigned short* __restrict__ A, long sAz,
    const unsigned short* __restrict__ B, long sBz, int bzMask,
    void* __restrict__ Cout, const float* __restrict__ bias, float scale,
    int M, int N, int K, int logSeq, int headBase)
{
  __shared__ unsigned short Al[128 * 32];
  __shared__ unsigned short Bl[128 * 32];
  const int tid = threadIdx.x;
  const int lane = tid & 63, wave = tid >> 6;
  const int z = blockIdx.z;
  const int m0 = blockIdx.y * 128, n0 = blockIdx.x * 128;
  const unsigned short* Az = A + (long)z * sAz;
  const unsigned short* Bz = B + (long)(z & bzMask) * sBz;
  if constexpr (MODE == 6) Bz = B + (long)(m0 >> 12) * 1048576;
  const int lr = lane & 15, lk = lane >> 4;
  const int wr = wave >> 1, wc = wave & 1;

  f32x4 acc[4][4] = {};

  const unsigned short* ga = Az + (long)(m0 + (tid >> 2)) * K + (tid & 3) * 8;
  const unsigned short* gb = Bz + (long)(n0 + (tid >> 2)) * K + (tid & 3) * 8;
  unsigned short* lA = Al + wave * 512;
  unsigned short* lB = Bl + wave * 512;
  const long rowStep = (long)64 * K;

  for (int kt = 0; kt < K; kt += 32){
    GLDS16(ga + kt,           lA);
    GLDS16(ga + kt + rowStep, lA + 64 * 32);
    GLDS16(gb + kt,           lB);
    GLDS16(gb + kt + rowStep, lB + 64 * 32);
    __syncthreads();
    bf16x8 af[4], bfr[4];
    #pragma unroll
    for (int mi = 0; mi < 4; mi++) af[mi]  = *(const bf16x8*)&Al[(wr * 64 + mi * 16 + lr) * 32 + lk * 8];
    #pragma unroll
    for (int ni = 0; ni < 4; ni++) bfr[ni] = *(const bf16x8*)&Bl[(wc * 64 + ni * 16 + lr) * 32 + lk * 8];
    #pragma unroll
    for (int mi = 0; mi < 4; mi++)
      #pragma unroll
      for (int ni = 0; ni < 4; ni++)
        acc[mi][ni] = __builtin_amdgcn_mfma_f32_16x16x32_bf16(af[mi], bfr[ni], acc[mi][ni], 0, 0, 0);
    __syncthreads();
  }

  #pragma unroll
  for (int mi = 0; mi < 4; mi++){
    #pragma unroll
    for (int ni = 0; ni < 4; ni++){
      #pragma unroll
      for (int r = 0; r < 4; r++){
        const int row = m0 + wr * 64 + mi * 16 + (lane >> 4) * 4 + r;  // verified C layout
        const int col = n0 + wc * 64 + ni * 16 + (lane & 15);
        float v = acc[mi][ni][r];
        if constexpr (MODE == 0){
          ((unsigned short*)Cout)[(long)z * M * N + (long)row * N + col] = f2bf(v);
        } else { // MODE 6
          const int seg = row >> 12;
          float sc = (seg == 0) ? scale : 1.0f;
          v = (v + bias[(seg << 10) + col]) * sc;
          long idx = (((long)(row >> 10) * 8 + (col >> 7)) * 1024 + (row & 1023)) * 128 + (col & 127);
          ((unsigned short*)Cout)[idx] = f2bf(v);
        }
      }
    }
  }
}

// ---------------- GEMM64: 64x128 tile, BK=32, 4 waves (each 16 rows x 128 cols) ----------------
// MODE 2: f32 out [M][N], +bias       (final projection)
// MODE 5: bf16 out, acc/sumexp[z*1024+row], PV remap -> oh[b][i][h*128+dk]
template<int MODE>
__global__ __launch_bounds__(256) void k_gemm64(
    const unsigned short* __restrict__ A, long sAz,
    const unsigned short* __restrict__ B, long sBz, int bzMask,
    void* __restrict__ Cout, const float* __restrict__ bias, float scale,
    int M, int N, int K)
{
  __shared__ unsigned short Al[64 * 32];    // 4 KB
  __shared__ unsigned short Bl[128 * 32];   // 8 KB
  const int tid = threadIdx.x;
  const int lane = tid & 63, wave = tid >> 6;
  const int z = blockIdx.z;
  const int m0 = blockIdx.y * 64, n0 = blockIdx.x * 128;
  const unsigned short* Az = A + (long)z * sAz;
  const unsigned short* Bz = B + (long)(z & bzMask) * sBz;
  const int lr = lane & 15, lk = lane >> 4;

  f32x4 acc[8] = {};

  const unsigned short* ga = Az + (long)(m0 + (tid >> 2)) * K + (tid & 3) * 8;
  const unsigned short* gb = Bz + (long)(n0 + (tid >> 2)) * K + (tid & 3) * 8;
  unsigned short* lA = Al + wave * 512;
  unsigned short* lB = Bl + wave * 512;
  const long rowStep = (long)64 * K;

  for (int kt = 0; kt < K; kt += 32){
    GLDS16(ga + kt,           lA);
    GLDS16(gb + kt,           lB);
    GLDS16(gb + kt + rowStep, lB + 64 * 32);
    __syncthreads();
    bf16x8 af = *(const bf16x8*)&Al[(wave * 16 + lr) * 32 + lk * 8];
    #pragma unroll
    for (int ni = 0; ni < 8; ni++){
      bf16x8 bfr = *(const bf16x8*)&Bl[(ni * 16 + lr) * 32 + lk * 8];
      acc[ni] = __builtin_amdgcn_mfma_f32_16x16x32_bf16(af, bfr, acc[ni], 0, 0, 0);
    }
    __syncthreads();
  }

  #pragma unroll
  for (int ni = 0; ni < 8; ni++){
    #pragma unroll
    for (int r = 0; r < 4; r++){
      const int row = m0 + wave * 16 + (lane >> 4) * 4 + r;  // verified C layout
      const int col = n0 + ni * 16 + (lane & 15);
      float v = acc[ni][r];
      if constexpr (MODE == 2){
        ((float*)Cout)[(long)row * N + col] = v + bias[col];
      } else { // MODE 5: PV normalize + remap
        float se = bias[(long)z * 1024 + row];
        v = v / se;
        ((unsigned short*)Cout)[((long)(z >> 3) * 1024 + row) * 1024 + (z & 7) * 128 + col] = f2bf(v);
      }
    }
  }
}

// ---------------- merged rel projections: 4 (A,B,C,bias,scale,headBase) sets ----------------
struct RelArgs { const unsigned short* A[4]; const unsigned short* B[4];
                 unsigned short* C[4]; const float* bias[4]; float scale[4]; int hb[4]; };
__global__ __launch_bounds__(256) void k_relproj(RelArgs a){
  __shared__ unsigned short Al[128 * 32];
  __shared__ unsigned short Bl[128 * 32];
  const int tid = threadIdx.x;
  const int lane = tid & 63, wave = tid >> 6;
  const int z = blockIdx.z;   // which projection
  const int m0 = blockIdx.y * 128, n0 = blockIdx.x * 128;
  const int lr = lane & 15, lk = lane >> 4;
  const int wr = wave >> 1, wc = wave & 1;
  const int K = 1024;

  f32x4 acc[4][4] = {};
  const unsigned short* ga = a.A[z] + (long)(m0 + (tid >> 2)) * K + (tid & 3) * 8;
  const unsigned short* gb = a.B[z] + (long)(n0 + (tid >> 2)) * K + (tid & 3) * 8;
  unsigned short* lA = Al + wave * 512;
  unsigned short* lB = Bl + wave * 512;
  const long rowStep = (long)64 * K;

  for (int kt = 0; kt < K; kt += 32){
    GLDS16(ga + kt,           lA);
    GLDS16(ga + kt + rowStep, lA + 64 * 32);
    GLDS16(gb + kt,           lB);
    GLDS16(gb + kt + rowStep, lB + 64 * 32);
    __syncthreads();
    bf16x8 af[4], bfr[4];
    #pragma unroll
    for (int mi = 0; mi < 4; mi++) af[mi]  = *(const bf16x8*)&Al[(wr * 64 + mi * 16 + lr) * 32 + lk * 8];
    #pragma unroll
    for (int ni = 0; ni < 4; ni++) bfr[ni] = *(const bf16x8*)&Bl[(wc * 64 + ni * 16 + lr) * 32 + lk * 8];
    #pragma unroll
    for (int mi = 0; mi < 4; mi++)
      #pragma unroll
      for (int ni = 0; ni < 4; ni++)
        acc[mi][ni] = __builtin_amdgcn_mfma_f32_16x16x32_bf16(af[mi], bfr[ni], acc[mi][ni], 0, 0, 0);
    __syncthreads();
  }

  const float scl = a.scale[z];
  const float* bias = a.bias[z];
  unsigned short* C = a.C[z];
  const int hb = a.hb[z];
  #pragma unroll
  for (int mi = 0; mi < 4; mi++){
    #pragma unroll
    for (int ni = 0; ni < 4; ni++){
      #pragma unroll
      for (int r = 0; r < 4; r++){
        const int row = m0 + wr * 64 + mi * 16 + (lane >> 4) * 4 + r;
        const int col = n0 + wc * 64 + ni * 16 + (lane & 15);
        float v = (acc[mi][ni][r] + bias[col]) * scl;
        long idx = (((long)(hb + (col >> 7))) * 512 + row) * 128 + (col & 127);
        C[idx] = f2bf(v);
      }
    }
  }
}

// ---------------- fused score: S[z][i][j] = c2c(q.k) + p2c gather (one S write) ----------------
// WAVE-AUTONOMOUS: block = 32 j x 1024 i, 4 waves; wave w owns j-slice (w&1)*16 and
// i-half (w>>1)*512. Per 64-i strip a wave: 16x256B-contiguous rel loads (full
// coalescing along i), p2c gather from LDS Ptl (wave-uniform row per load), 16 MFMA c2c
// (k-frags in registers), exchange via PER-WAVE LDS tiles (same-wave lgkmcnt only),
// 32B-contiguous S writes. ZERO loop barriers -> waves free-run, stalls are private.
// LDS 51.5 KB -> 3 blocks/CU (12 waves).
__global__ __launch_bounds__(256) void k_scorep2c(
    const unsigned short* __restrict__ qs, const unsigned short* __restrict__ kk,
    const unsigned short* __restrict__ Pt, const int* __restrict__ rel,
    unsigned short* __restrict__ S)
{
  __shared__ unsigned short Ptl[32][512];      // 32 KB
  __shared__ unsigned short Tp[4][16][66];     // p2c exchange [wave][j-local][i-strip]
  __shared__ unsigned short Tc[4][64][20];     // c2c exchange [wave][i-strip][j-local]
  const int tid = threadIdx.x, l = tid & 63, w = tid >> 6;
  const int j0 = blockIdx.x * 32, z = blockIdx.y;
  const long zb = (long)z << 20;
  const int lr = l & 15, lk = l >> 4;
  const int jwL = (w & 1) * 16;          // local j-slice base
  const int jw  = j0 + jwL;              // global j base for this wave
  const int ibase = (w >> 1) * 512;      // i-half

  { // stage Pt rows (32 x 1KB, linear)
    const char* g = (const char*)(Pt + ((long)z * 1024 + j0) * 512);
    char* lb = (char*)&Ptl[0][0];
    #pragma unroll
    for (int it = 0; it < 8; it++)
      GLDS16(g + it * 4096 + w * 1024 + l * 16, lb + it * 4096 + w * 1024);
  }

  // k fragments for this wave's 16 j (invariant, register-resident)
  const unsigned short* kz = kk + (long)z * 131072;
  bf16x8 kf[4];
  #pragma unroll
  for (int kt = 0; kt < 4; kt++)
    kf[kt] = *(const bf16x8*)&kz[(jw + lr) * 128 + kt * 32 + lk * 8];

  const unsigned short* qz = qs + (long)z * 131072;
  const int* relw = rel + zb + (long)jw * 1024;   // this wave's 16 j-rows

  __syncthreads();   // Ptl staged (only barrier in the kernel)

  #pragma unroll 2
  for (int s = 0; s < 8; s++){
    const int i0 = ibase + s * 64;
    // rel: 16 loads, each 64 lanes x consecutive i = 256B contiguous
    int rv[16];
    #pragma unroll
    for (int jj = 0; jj < 16; jj++) rv[jj] = relw[jj * 1024 + i0 + l];
    // p2c gather: wave-uniform Ptl row per load, random col (~2 lanes/bank)
    #pragma unroll
    for (int jj = 0; jj < 16; jj++)
      Tp[w][jj][l] = Ptl[jwL + jj][rv[jj] & 511];
    // c2c: 4 i-subtiles x 16 j, K=128
    f32x4 acc[4] = {};
    #pragma unroll
    for (int kt = 0; kt < 4; kt++){
      #pragma unroll
      for (int sub = 0; sub < 4; sub++){
        bf16x8 af = *(const bf16x8*)&qz[(i0 + sub * 16 + lr) * 128 + kt * 32 + lk * 8];
        acc[sub] = __builtin_amdgcn_mfma_f32_16x16x32_bf16(af, kf[kt], acc[sub], 0, 0, 0);
      }
    }
    #pragma unroll
    for (int sub = 0; sub < 4; sub++)
      #pragma unroll
      for (int r = 0; r < 4; r++)
        Tc[w][sub * 16 + lk * 4 + r][lr] = f2bf(acc[sub][r]);   // verified C layout
    // same-wave LDS dependency (compiler inserts lgkmcnt); lane l owns row i0+l
    float f[16];
    #pragma unroll
    for (int jj = 0; jj < 16; jj++)
      f[jj] = bf2f(Tc[w][l][jj]) + bf2f(Tp[w][jj][l]);
    unsigned int aw[8];
    #pragma unroll
    for (int e = 0; e < 8; e++)
      aw[e] = (unsigned)f2bf(f[2*e]) | ((unsigned)f2bf(f[2*e+1]) << 16);
    unsigned short* sp = S + zb + (long)(i0 + l) * 1024 + jw;
    *(uint4*)sp       = make_uint4(aw[0], aw[1], aw[2], aw[3]);
    *(uint4*)(sp + 8) = make_uint4(aw[4], aw[5], aw[6], aw[7]);
  }
}

// ---------------- c2p + mask + exp (no-max softmax numerator) + row expsum ----------------
__global__ __launch_bounds__(256) void k_c2pexp(unsigned short* __restrict__ S,
    const unsigned short* __restrict__ Cc, const int* __restrict__ rel,
    const int* __restrict__ maskp, float* __restrict__ sumexp){
  __shared__ unsigned short Ccl[32][512];   // 32 KB
  const int tid = threadIdx.x, l = tid & 63, w = tid >> 6;
  const int z = blockIdx.y, i0 = blockIdx.x * 32;
  const long zb = (long)z << 20;
  {
    const char* g = (const char*)Cc + ((long)z * 1024 + i0) * 1024;  // 32 rows x 1KB
    char* lb = (char*)&Ccl[0][0];
    #pragma unroll
    for (int it = 0; it < 8; it++)
      GLDS16(g + it * 4096 + w * 1024 + l * 16, lb + it * 4096 + w * 1024);
  }
  __syncthreads();
  const int il = tid >> 3;            // row 0..31
  const int jq = (tid & 7) * 8;       // j offset within 64-strip
  const int i = i0 + il;
  unsigned short* srow = S + zb + (long)i * 1024;
  const int* relrow  = rel + zb + (long)i * 1024;
  const int* maskrow = maskp + (((long)(z >> 3)) << 20) + (long)i * 1024;
  const unsigned short* cl = &Ccl[il][0];
  float se = 0.f;
  for (int j0 = 0; j0 < 1024; j0 += 64){
    const int j = j0 + jq;
    uint4 a = *(const uint4*)(srow + j);
    int4 r0 = ((const int4*)(relrow + j))[0];
    int4 r1 = ((const int4*)(relrow + j))[1];
    int4 m0 = ((const int4*)(maskrow + j))[0];
    int4 m1 = ((const int4*)(maskrow + j))[1];
    unsigned int aw[4] = {a.x, a.y, a.z, a.w};
    float f[8];
    #pragma unroll
    for (int e = 0; e < 4; e++){
      f[2*e]   = bf2f((unsigned short)(aw[e] & 0xFFFFu));
      f[2*e+1] = bf2f((unsigned short)(aw[e] >> 16));
    }
    f[0] += bf2f(cl[r0.x & 511]); f[1] += bf2f(cl[r0.y & 511]);
    f[2] += bf2f(cl[r0.z & 511]); f[3] += bf2f(cl[r0.w & 511]);
    f[4] += bf2f(cl[r1.x & 511]); f[5] += bf2f(cl[r1.y & 511]);
    f[6] += bf2f(cl[r1.z & 511]); f[7] += bf2f(cl[r1.w & 511]);
    int mm[8] = {m0.x, m0.y, m0.z, m0.w, m1.x, m1.y, m1.z, m1.w};
    float p[8];
    #pragma unroll
    for (int e = 0; e < 8; e++){
      p[e] = (mm[e] == 1) ? 0.0f : __expf(f[e]);
      se += p[e];
    }
    #pragma unroll
    for (int e = 0; e < 4; e++)
      aw[e] = (unsigned)f2bf(p[2*e]) | ((unsigned)f2bf(p[2*e+1]) << 16);
    *(uint4*)(srow + j) = make_uint4(aw[0], aw[1], aw[2], aw[3]);
  }
  se += __shfl_xor(se, 1);
  se += __shfl_xor(se, 2);
  se += __shfl_xor(se, 4);
  if ((l & 7) == 0) sumexp[(long)z * 1024 + i] = se;
}

extern "C" void kernel_launch(void* const* d_in, const int* in_sizes, int n_in,
                              void* d_out, int out_size, void* d_ws, size_t ws_size,
                              hipStream_t stream){
  (void)in_sizes; (void)n_in; (void)out_size; (void)ws_size;
  const float* query = (const float*)d_in[0];
  const float* key_  = (const float*)d_in[1];
  const float* value = (const float*)d_in[2];
  const float* rele  = (const float*)d_in[3];
  const int*   rel   = (const int*)d_in[4];
  const int*   mask  = (const int*)d_in[5];
  const float* Wq = (const float*)d_in[6];  const float* bq = (const float*)d_in[7];
  const float* Wk = (const float*)d_in[8];  const float* bk = (const float*)d_in[9];
  const float* Wv = (const float*)d_in[10]; const float* bv = (const float*)d_in[11];
  const float* Wo = (const float*)d_in[12]; const float* bo = (const float*)d_in[13];
  const float* Wlq = (const float*)d_in[14]; const float* blq = (const float*)d_in[15];
  const float* Wlk = (const float*)d_in[16]; const float* blk = (const float*)d_in[17];
  const float* Wtq = (const float*)d_in[18]; const float* btq = (const float*)d_in[19];
  const float* Wtk = (const float*)d_in[20]; const float* btk = (const float*)d_in[21];

  char* ws = (char*)d_ws;
  auto U = [&](size_t off){ return (unsigned short*)(ws + off); };
  // region 0..64MB: score S; convert staging + small weights + biasPack (all dead
  // before the score write) alias into it
  unsigned short* S    = U(0);
  unsigned short* qf   = U(0);          // A for merged QKV proj (qf|kf|vf contiguous)
  unsigned short* lt   = U(25165824);   // rel_emb bf16: l then t
  unsigned short* WqT  = U(27262976);   // WqT|WkT|WvT contiguous
  unsigned short* WlqT = U(33554432);
  unsigned short* WlkT = U(34603008);
  unsigned short* WtqT = U(35651584);
  unsigned short* WtkT = U(36700160);
  float*  biasPack     = (float*)(ws + 38797312);  // 12 KB, inside S region (dead by score)
  unsigned short* WoT  = U(67108864);
  unsigned short* qs   = U(69206016);   // scaled q [B,H,N,DK]; qs|kk|vv contiguous
  float*          sumexp = (float*)(ws + 69206016);  // aliases qs (dead after score+Cc), 128KB
  unsigned short* kk   = U(77594624);
  unsigned short* vv   = U(85983232);
  unsigned short* oh   = U(85983232);   // out_heads aliases vv (vv dead after vtrans)
  unsigned short* vT   = U(94371840);   // v^T [B,H,DK,N]
  unsigned short* lqs  = U(102760448);  // scaled lq [H,L,DK]
  unsigned short* lks  = U(103809024);  // lk [H,L,DK]
  unsigned short* Pt   = U(104857600);  // p2c table [B,H,N(j),L(r)]
  unsigned short* Cc   = U(138412032);  // c2p table [B,H,N(i),L(l)]

  const float invs = 1.0f / sqrtf(384.0f);  // 1/sqrt(3*DK)
  dim3 b256(256), b644(64, 4);

  // merged converts + bias pack
  k_convert4<<<2048, b256, 0, stream>>>(query, key_, value, rele, (ushort4*)ws,
                                        bq, bk, bv, biasPack);

  // merged weight transposes
  WtArgs wa;
  wa.W[0]=Wq;  wa.Wd[0]=WqT;           wa.N[0]=1024;
  wa.W[1]=Wk;  wa.Wd[1]=U(29360128);   wa.N[1]=1024;
  wa.W[2]=Wv;  wa.Wd[2]=U(31457280);   wa.N[2]=1024;
  wa.W[3]=Wo;  wa.Wd[3]=WoT;           wa.N[3]=1024;
  wa.W[4]=Wlq; wa.Wd[4]=WlqT;          wa.N[4]=512;
  wa.W[5]=Wlk; wa.Wd[5]=WlkT;          wa.N[5]=512;
  wa.W[6]=Wtq; wa.Wd[6]=WtqT;          wa.N[6]=512;
  wa.W[7]=Wtk; wa.Wd[7]=WtkT;          wa.N[7]=512;
  k_wtrans8<<<dim3(16,16,8), b644, 0, stream>>>(wa);

  // merged q/k/v projections: M=12288 (scale folded into q covers /sqrt(384) of c2c,c2p)
  k_gemm<6><<<dim3(8,96,1), b256, 0, stream>>>(qf,0, WqT,0,0, qs, biasPack, invs,
                                               12288,1024,1024, 10,0);

  // merged rel projections (scale folded into lq covers /sqrt(384) of p2c)
  RelArgs ra;
  ra.A[0]=lt;        ra.B[0]=WlqT; ra.C[0]=lqs; ra.bias[0]=blq; ra.scale[0]=invs; ra.hb[0]=0;
  ra.A[1]=lt+524288; ra.B[1]=WtqT; ra.C[1]=lqs; ra.bias[1]=btq; ra.scale[1]=invs; ra.hb[1]=4;
  ra.A[2]=lt;        ra.B[2]=WlkT; ra.C[2]=lks; ra.bias[2]=blk; ra.scale[2]=1.0f; ra.hb[2]=0;
  ra.A[3]=lt+524288; ra.B[3]=WtkT; ra.C[3]=lks; ra.bias[3]=btk; ra.scale[3]=1.0f; ra.hb[3]=4;
  k_relproj<<<dim3(4,4,4), b256, 0, stream>>>(ra);

  k_vtrans<<<dim3(2,16,32), b644, 0, stream>>>(vv, vT);

  // tables: Pt[z][j][r] = k_j . lq_r ; Cc[z][i][l] = q_i . lk_l
  k_gemm<0><<<dim3(4,8,32), b256, 0, stream>>>(kk,131072, lqs,65536,7, Pt, nullptr,1.0f, 1024,512,128, 0,0);
  k_gemm<0><<<dim3(4,8,32), b256, 0, stream>>>(qs,131072, lks,65536,7, Cc, nullptr,1.0f, 1024,512,128, 0,0);

  // fused score: c2c MFMA + p2c gather -> S (wave-autonomous, zero loop barriers)
  k_scorep2c<<<dim3(32,32), b256, 0, stream>>>(qs, kk, Pt, rel, S);

  // S <- exp(S + c2p + mask) in place (no-max softmax numerator), row sums -> sumexp
  k_c2pexp<<<dim3(32,32), b256, 0, stream>>>(S, Cc, rel, mask, sumexp);

  // oh = (P @ v) / sumexp[row]   (64-row tiles -> 512 blocks = 2/CU)
  k_gemm64<5><<<dim3(1,16,32), b256, 0, stream>>>(S,1048576, vT,131072,-1, oh, sumexp, 1.0f, 1024,128,1024);

  // final: d_out = out_heads @ Wo + bo   (f32 out; 64-row tiles -> 512 blocks = 2/CU)
  k_gemm64<2><<<dim3(8,64,1), b256, 0, stream>>>(oh,0, WoT,0,0, d_out, bo, 1.0f, 4096,1024,1024);
}

// Round 16
// 340.042 us; speedup vs baseline: 1.2366x; 1.2366x over previous
//
#include <hip/hip_runtime.h>
#include <hip/hip_bf16.h>
#include <stdint.h>
#include <math.h>

// B=4, N=1024, D=1024, H=8, DK=128, L=512. All internal tensors bf16 in ws.
// GEMM convention everywhere: C[m,n] = sum_k A[m,k]*B[n,k]  (B stored [N,K]).

typedef __attribute__((ext_vector_type(8))) __bf16 bf16x8;
typedef __attribute__((ext_vector_type(4))) float f32x4;

#define DEV static __device__ __forceinline__

DEV float bf2f(unsigned short u){ union { unsigned int i; float f; } x; x.i = ((unsigned int)u) << 16; return x.f; }
DEV unsigned short f2bf(float f){ union { float f; unsigned int i; } x; x.f = f;
  unsigned int r = x.i + 0x7FFFu + ((x.i >> 16) & 1u); return (unsigned short)(r >> 16); }

#define GLDS16(gp, lp) __builtin_amdgcn_global_load_lds( \
    (const __attribute__((address_space(1))) void*)(gp), \
    (__attribute__((address_space(3))) void*)(lp), 16, 0, 0)

// ---------------- merged f32 -> bf16 convert: query,key,value,rel_emb + bias pack ----------------
__global__ __launch_bounds__(256) void k_convert4(const float* __restrict__ q,
    const float* __restrict__ k, const float* __restrict__ v,
    const float* __restrict__ r, ushort4* __restrict__ dst,
    const float* __restrict__ bq, const float* __restrict__ bk,
    const float* __restrict__ bv, float* __restrict__ biasPack){
  const int total = 3407872;   // 3*1048576 + 262144 float4 groups
  int gid = blockIdx.x * blockDim.x + threadIdx.x;
  if (gid < 3072)
    biasPack[gid] = (gid < 1024) ? bq[gid] : (gid < 2048 ? bk[gid - 1024] : bv[gid - 2048]);
  for (int i = gid; i < total; i += gridDim.x * blockDim.x){
    const float4* s;
    if (i < 2097152) s = (i < 1048576) ? ((const float4*)q + i) : ((const float4*)k + (i - 1048576));
    else             s = (i < 3145728) ? ((const float4*)v + (i - 2097152)) : ((const float4*)r + (i - 3145728));
    float4 x = *s;
    ushort4 o; o.x = f2bf(x.x); o.y = f2bf(x.y); o.z = f2bf(x.z); o.w = f2bf(x.w);
    dst[i] = o;
  }
}

// ---------------- merged weight transpose: 8 weights, W [1024,N] f32 -> WT [N,1024] bf16 ----
struct WtArgs { const float* W[8]; unsigned short* Wd[8]; int N[8]; };
__global__ __launch_bounds__(256) void k_wtrans8(WtArgs a){
  __shared__ unsigned short t[64][65];
  const int z = blockIdx.z, N = a.N[z];
  const int n0 = blockIdx.x * 64, k0 = blockIdx.y * 64;
  if (n0 >= N) return;
  const float* W = a.W[z];
  unsigned short* WT = a.Wd[z];
  int tx = threadIdx.x, ty = threadIdx.y;
  for (int r = ty; r < 64; r += 4) t[r][tx] = f2bf(W[(long)(k0 + r) * N + n0 + tx]);
  __syncthreads();
  for (int r = ty; r < 64; r += 4) WT[(long)(n0 + r) * 1024 + k0 + tx] = t[tx][r];
}

// ---------------- v [z][1024][128] -> vT [z][128][1024] (bf16) ----------------
__global__ __launch_bounds__(256) void k_vtrans(const unsigned short* __restrict__ V,
                                                unsigned short* __restrict__ VT){
  __shared__ unsigned short t[64][65];
  int z = blockIdx.z, d0 = blockIdx.x * 64, j0 = blockIdx.y * 64;
  int tx = threadIdx.x, ty = threadIdx.y;
  const unsigned short* v = V + (long)z * 131072;
  unsigned short* vt = VT + (long)z * 131072;
  for (int r = ty; r < 64; r += 4) t[r][tx] = v[(j0 + r) * 128 + d0 + tx];
  __syncthreads();
  for (int r = ty; r < 64; r += 4) vt[(d0 + r) * 1024 + j0 + tx] = t[tx][r];
}

// ---------------- GEMM: 128x128 tile, BK=32, 4 waves (2x2), m97 structure ----------------
// MODE 0: plain bf16 out [z][M][N]                       (tables)
// MODE 6: merged q/k/v projection: M=12288, B segment by m0>>12, packed bias,
//         scale only on segment 0, head-split remap into contiguous qs|kk|vv
template<int MODE>
__global__ __launch_bounds__(256) void k_gemm(
    const unsigned short* __restrict__ A, long sAz,
    const unsigned short* __restrict__ B, long sBz, int bzMask,
    void* __restrict__ Cout, const float* __restrict__ bias, float scale,
    int M, int N, int K, int logSeq, int headBase)
{
  __shared__ unsigned short Al[128 * 32];
  __shared__ unsigned short Bl[128 * 32];
  const int tid = threadIdx.x;
  const int lane = tid & 63, wave = tid >> 6;
  const int z = blockIdx.z;
  const int m0 = blockIdx.y * 128, n0 = blockIdx.x * 128;
  const unsigned short* Az = A + (long)z * sAz;
  const unsigned short* Bz = B + (long)(z & bzMask) * sBz;
  if constexpr (MODE == 6) Bz = B + (long)(m0 >> 12) * 1048576;
  const int lr = lane & 15, lk = lane >> 4;
  const int wr = wave >> 1, wc = wave & 1;

  f32x4 acc[4][4] = {};

  const unsigned short* ga = Az + (long)(m0 + (tid >> 2)) * K + (tid & 3) * 8;
  const unsigned short* gb = Bz + (long)(n0 + (tid >> 2)) * K + (tid & 3) * 8;
  unsigned short* lA = Al + wave * 512;
  unsigned short* lB = Bl + wave * 512;
  const long rowStep = (long)64 * K;

  for (int kt = 0; kt < K; kt += 32){
    GLDS16(ga + kt,           lA);
    GLDS16(ga + kt + rowStep, lA + 64 * 32);
    GLDS16(gb + kt,           lB);
    GLDS16(gb + kt + rowStep, lB + 64 * 32);
    __syncthreads();
    bf16x8 af[4], bfr[4];
    #pragma unroll
    for (int mi = 0; mi < 4; mi++) af[mi]  = *(const bf16x8*)&Al[(wr * 64 + mi * 16 + lr) * 32 + lk * 8];
    #pragma unroll
    for (int ni = 0; ni < 4; ni++) bfr[ni] = *(const bf16x8*)&Bl[(wc * 64 + ni * 16 + lr) * 32 + lk * 8];
    #pragma unroll
    for (int mi = 0; mi < 4; mi++)
      #pragma unroll
      for (int ni = 0; ni < 4; ni++)
        acc[mi][ni] = __builtin_amdgcn_mfma_f32_16x16x32_bf16(af[mi], bfr[ni], acc[mi][ni], 0, 0, 0);
    __syncthreads();
  }

  #pragma unroll
  for (int mi = 0; mi < 4; mi++){
    #pragma unroll
    for (int ni = 0; ni < 4; ni++){
      #pragma unroll
      for (int r = 0; r < 4; r++){
        const int row = m0 + wr * 64 + mi * 16 + (lane >> 4) * 4 + r;  // verified C layout
        const int col = n0 + wc * 64 + ni * 16 + (lane & 15);
        float v = acc[mi][ni][r];
        if constexpr (MODE == 0){
          ((unsigned short*)Cout)[(long)z * M * N + (long)row * N + col] = f2bf(v);
        } else { // MODE 6
          const int seg = row >> 12;
          float sc = (seg == 0) ? scale : 1.0f;
          v = (v + bias[(seg << 10) + col]) * sc;
          long idx = (((long)(row >> 10) * 8 + (col >> 7)) * 1024 + (row & 1023)) * 128 + (col & 127);
          ((unsigned short*)Cout)[idx] = f2bf(v);
        }
      }
    }
  }
}

// ---------------- GEMM64: 64x128 tile, BK=32, 4 waves (each 16 rows x 128 cols) ----------------
// MODE 2: f32 out [M][N], +bias       (final projection)
// MODE 5: bf16 out, acc/sumexp[z*1024+row], PV remap -> oh[b][i][h*128+dk]
template<int MODE>
__global__ __launch_bounds__(256) void k_gemm64(
    const unsigned short* __restrict__ A, long sAz,
    const unsigned short* __restrict__ B, long sBz, int bzMask,
    void* __restrict__ Cout, const float* __restrict__ bias, float scale,
    int M, int N, int K)
{
  __shared__ unsigned short Al[64 * 32];    // 4 KB
  __shared__ unsigned short Bl[128 * 32];   // 8 KB
  const int tid = threadIdx.x;
  const int lane = tid & 63, wave = tid >> 6;
  const int z = blockIdx.z;
  const int m0 = blockIdx.y * 64, n0 = blockIdx.x * 128;
  const unsigned short* Az = A + (long)z * sAz;
  const unsigned short* Bz = B + (long)(z & bzMask) * sBz;
  const int lr = lane & 15, lk = lane >> 4;

  f32x4 acc[8] = {};

  const unsigned short* ga = Az + (long)(m0 + (tid >> 2)) * K + (tid & 3) * 8;
  const unsigned short* gb = Bz + (long)(n0 + (tid >> 2)) * K + (tid & 3) * 8;
  unsigned short* lA = Al + wave * 512;
  unsigned short* lB = Bl + wave * 512;
  const long rowStep = (long)64 * K;

  for (int kt = 0; kt < K; kt += 32){
    GLDS16(ga + kt,           lA);
    GLDS16(gb + kt,           lB);
    GLDS16(gb + kt + rowStep, lB + 64 * 32);
    __syncthreads();
    bf16x8 af = *(const bf16x8*)&Al[(wave * 16 + lr) * 32 + lk * 8];
    #pragma unroll
    for (int ni = 0; ni < 8; ni++){
      bf16x8 bfr = *(const bf16x8*)&Bl[(ni * 16 + lr) * 32 + lk * 8];
      acc[ni] = __builtin_amdgcn_mfma_f32_16x16x32_bf16(af, bfr, acc[ni], 0, 0, 0);
    }
    __syncthreads();
  }

  #pragma unroll
  for (int ni = 0; ni < 8; ni++){
    #pragma unroll
    for (int r = 0; r < 4; r++){
      const int row = m0 + wave * 16 + (lane >> 4) * 4 + r;  // verified C layout
      const int col = n0 + ni * 16 + (lane & 15);
      float v = acc[ni][r];
      if constexpr (MODE == 2){
        ((float*)Cout)[(long)row * N + col] = v + bias[col];
      } else { // MODE 5: PV normalize + remap
        float se = bias[(long)z * 1024 + row];
        v = v / se;
        ((unsigned short*)Cout)[((long)(z >> 3) * 1024 + row) * 1024 + (z & 7) * 128 + col] = f2bf(v);
      }
    }
  }
}

// ---------------- merged rel projections: 4 (A,B,C,bias,scale,headBase) sets ----------------
struct RelArgs { const unsigned short* A[4]; const unsigned short* B[4];
                 unsigned short* C[4]; const float* bias[4]; float scale[4]; int hb[4]; };
__global__ __launch_bounds__(256) void k_relproj(RelArgs a){
  __shared__ unsigned short Al[128 * 32];
  __shared__ unsigned short Bl[128 * 32];
  const int tid = threadIdx.x;
  const int lane = tid & 63, wave = tid >> 6;
  const int z = blockIdx.z;   // which projection
  const int m0 = blockIdx.y * 128, n0 = blockIdx.x * 128;
  const int lr = lane & 15, lk = lane >> 4;
  const int wr = wave >> 1, wc = wave & 1;
  const int K = 1024;

  f32x4 acc[4][4] = {};
  const unsigned short* ga = a.A[z] + (long)(m0 + (tid >> 2)) * K + (tid & 3) * 8;
  const unsigned short* gb = a.B[z] + (long)(n0 + (tid >> 2)) * K + (tid & 3) * 8;
  unsigned short* lA = Al + wave * 512;
  unsigned short* lB = Bl + wave * 512;
  const long rowStep = (long)64 * K;

  for (int kt = 0; kt < K; kt += 32){
    GLDS16(ga + kt,           lA);
    GLDS16(ga + kt + rowStep, lA + 64 * 32);
    GLDS16(gb + kt,           lB);
    GLDS16(gb + kt + rowStep, lB + 64 * 32);
    __syncthreads();
    bf16x8 af[4], bfr[4];
    #pragma unroll
    for (int mi = 0; mi < 4; mi++) af[mi]  = *(const bf16x8*)&Al[(wr * 64 + mi * 16 + lr) * 32 + lk * 8];
    #pragma unroll
    for (int ni = 0; ni < 4; ni++) bfr[ni] = *(const bf16x8*)&Bl[(wc * 64 + ni * 16 + lr) * 32 + lk * 8];
    #pragma unroll
    for (int mi = 0; mi < 4; mi++)
      #pragma unroll
      for (int ni = 0; ni < 4; ni++)
        acc[mi][ni] = __builtin_amdgcn_mfma_f32_16x16x32_bf16(af[mi], bfr[ni], acc[mi][ni], 0, 0, 0);
    __syncthreads();
  }

  const float scl = a.scale[z];
  const float* bias = a.bias[z];
  unsigned short* C = a.C[z];
  const int hb = a.hb[z];
  #pragma unroll
  for (int mi = 0; mi < 4; mi++){
    #pragma unroll
    for (int ni = 0; ni < 4; ni++){
      #pragma unroll
      for (int r = 0; r < 4; r++){
        const int row = m0 + wr * 64 + mi * 16 + (lane >> 4) * 4 + r;
        const int col = n0 + wc * 64 + ni * 16 + (lane & 15);
        float v = (acc[mi][ni][r] + bias[col]) * scl;
        long idx = (((long)(hb + (col >> 7))) * 512 + row) * 128 + (col & 127);
        C[idx] = f2bf(v);
      }
    }
  }
}

// ---------------- fused score: S[z][i][j] = c2c(q.k) + p2c gather (one S write) ----------------
// Round-12 structure with DEPTH-2 prefetch: per-strip compute (~300 cy) < HBM latency
// (~900 cy), so depth-1 re-stalled every strip. Strips s+1 AND s+2 are in flight across
// the raw barrier (lgkmcnt-only wait; vmcnt untouched). T double-buffered (2 slots
// suffice: writer of T[s&1] at s+2 is after strip-s reader via the s+1 barrier).
__global__ __launch_bounds__(256) void k_scorep2c(
    const unsigned short* __restrict__ qs, const unsigned short* __restrict__ kk,
    const unsigned short* __restrict__ Pt, const int* __restrict__ rel,
    unsigned short* __restrict__ S)
{
  __shared__ unsigned short Ptl[32][512];      // 32 KB
  __shared__ unsigned short T[2][32][66];      // p2c exchange, double-buffered
  __shared__ unsigned short Tc[4][16][40];     // c2c exchange per wave (same-wave only)
  const int tid = threadIdx.x, l = tid & 63, w = tid >> 6;
  const int j0 = blockIdx.x * 32, z = blockIdx.y, ih = blockIdx.z;
  const long zb = (long)z << 20;
  const int lr = l & 15, lk = l >> 4;

  { // stage Pt rows (32 x 1KB, linear)
    const char* g = (const char*)(Pt + ((long)z * 1024 + j0) * 512);
    char* lb = (char*)&Ptl[0][0];
    #pragma unroll
    for (int it = 0; it < 8; it++)
      GLDS16(g + it * 4096 + w * 1024 + l * 16, lb + it * 4096 + w * 1024);
  }

  // k fragments: direct global->register, invariant across strips
  const unsigned short* kz = kk + (long)z * 131072;
  bf16x8 kf[4][2];
  #pragma unroll
  for (int kt = 0; kt < 4; kt++)
    #pragma unroll
    for (int ni = 0; ni < 2; ni++)
      kf[kt][ni] = *(const bf16x8*)&kz[(j0 + ni * 16 + lr) * 128 + kt * 32 + lk * 8];

  const int jb = w * 8;               // gather-phase j-rows for this wave
  const int il = tid >> 2;            // add-phase strip-local i (0..63)
  const int jq = (tid & 3) * 8;       // add-phase j-quarter
  const unsigned short* qz = qs + (long)z * 131072;
  const int* relb = rel + zb + (long)(j0 + jb) * 1024 + l;

  // prologue: prefetch strips 0 and 1
  int rv0[8], rv1[8]; bf16x8 af0[4], af1[4];
  {
    const int ia = ih * 512, ib2 = ia + 64;
    #pragma unroll
    for (int jj = 0; jj < 8; jj++) rv0[jj] = relb[jj * 1024 + ia];
    #pragma unroll
    for (int kt = 0; kt < 4; kt++)
      af0[kt] = *(const bf16x8*)&qz[(ia + w * 16 + lr) * 128 + kt * 32 + lk * 8];
    #pragma unroll
    for (int jj = 0; jj < 8; jj++) rv1[jj] = relb[jj * 1024 + ib2];
    #pragma unroll
    for (int kt = 0; kt < 4; kt++)
      af1[kt] = *(const bf16x8*)&qz[(ib2 + w * 16 + lr) * 128 + kt * 32 + lk * 8];
  }
  __syncthreads();   // Ptl staged (full drain here is fine: once per block)

  for (int s = 0; s < 8; s++){
    const int i0 = ih * 512 + s * 64;
    const int tb = s & 1;
    // gather phase (uses strip-s prefetch rv0)
    unsigned short vals[8];
    #pragma unroll
    for (int jj = 0; jj < 8; jj++) vals[jj] = Ptl[jb + jj][rv0[jj] & 511];
    #pragma unroll
    for (int jj = 0; jj < 8; jj++) T[tb][jb + jj][l] = vals[jj];
    // prefetch strip s+2 (stays in flight across barriers)
    int rvn[8] = {}; bf16x8 afn[4] = {};
    if (s < 6){
      const int i2 = i0 + 128;
      #pragma unroll
      for (int jj = 0; jj < 8; jj++) rvn[jj] = relb[jj * 1024 + i2];
      #pragma unroll
      for (int kt = 0; kt < 4; kt++)
        afn[kt] = *(const bf16x8*)&qz[(i2 + w * 16 + lr) * 128 + kt * 32 + lk * 8];
    }
    asm volatile("s_waitcnt lgkmcnt(0)" ::: "memory");  // T writes visible; vmcnt untouched
    __builtin_amdgcn_s_barrier();
    __builtin_amdgcn_sched_barrier(0);                  // rule #18: pin ordering after raw barrier

    // compute phase: wave w computes strip rows w*16..w*16+16 x 32 j
    f32x4 acc0 = {}, acc1 = {};
    #pragma unroll
    for (int kt = 0; kt < 4; kt++){
      acc0 = __builtin_amdgcn_mfma_f32_16x16x32_bf16(af0[kt], kf[kt][0], acc0, 0, 0, 0);
      acc1 = __builtin_amdgcn_mfma_f32_16x16x32_bf16(af0[kt], kf[kt][1], acc1, 0, 0, 0);
    }
    #pragma unroll
    for (int r = 0; r < 4; r++){
      Tc[w][lk * 4 + r][lr]      = f2bf(acc0[r]);
      Tc[w][lk * 4 + r][16 + lr] = f2bf(acc1[r]);
    }
    // same-wave LDS dependency (compiler inserts lgkmcnt); T cross-wave covered by barrier
    float f[8];
    #pragma unroll
    for (int jj = 0; jj < 8; jj++)
      f[jj] = bf2f(Tc[w][l >> 2][jq + jj]) + bf2f(T[tb][jq + jj][il]);
    unsigned int aw[4];
    #pragma unroll
    for (int e = 0; e < 4; e++)
      aw[e] = (unsigned)f2bf(f[2*e]) | ((unsigned)f2bf(f[2*e+1]) << 16);
    *(uint4*)(S + zb + (long)(i0 + il) * 1024 + j0 + jq) = make_uint4(aw[0], aw[1], aw[2], aw[3]);

    // rotate prefetch registers: s+1 -> current, s+2 -> next
    #pragma unroll
    for (int jj = 0; jj < 8; jj++){ rv0[jj] = rv1[jj]; rv1[jj] = rvn[jj]; }
    #pragma unroll
    for (int kt = 0; kt < 4; kt++){ af0[kt] = af1[kt]; af1[kt] = afn[kt]; }
  }
}

// ---------------- c2p + mask + exp (no-max softmax numerator) + row expsum ----------------
__global__ __launch_bounds__(256) void k_c2pexp(unsigned short* __restrict__ S,
    const unsigned short* __restrict__ Cc, const int* __restrict__ rel,
    const int* __restrict__ maskp, float* __restrict__ sumexp){
  __shared__ unsigned short Ccl[32][512];   // 32 KB
  const int tid = threadIdx.x, l = tid & 63, w = tid >> 6;
  const int z = blockIdx.y, i0 = blockIdx.x * 32;
  const long zb = (long)z << 20;
  {
    const char* g = (const char*)Cc + ((long)z * 1024 + i0) * 1024;  // 32 rows x 1KB
    char* lb = (char*)&Ccl[0][0];
    #pragma unroll
    for (int it = 0; it < 8; it++)
      GLDS16(g + it * 4096 + w * 1024 + l * 16, lb + it * 4096 + w * 1024);
  }
  __syncthreads();
  const int il = tid >> 3;            // row 0..31
  const int jq = (tid & 7) * 8;       // j offset within 64-strip
  const int i = i0 + il;
  unsigned short* srow = S + zb + (long)i * 1024;
  const int* relrow  = rel + zb + (long)i * 1024;
  const int* maskrow = maskp + (((long)(z >> 3)) << 20) + (long)i * 1024;
  const unsigned short* cl = &Ccl[il][0];
  float se = 0.f;
  for (int j0 = 0; j0 < 1024; j0 += 64){
    const int j = j0 + jq;
    uint4 a = *(const uint4*)(srow + j);
    int4 r0 = ((const int4*)(relrow + j))[0];
    int4 r1 = ((const int4*)(relrow + j))[1];
    int4 m0 = ((const int4*)(maskrow + j))[0];
    int4 m1 = ((const int4*)(maskrow + j))[1];
    unsigned int aw[4] = {a.x, a.y, a.z, a.w};
    float f[8];
    #pragma unroll
    for (int e = 0; e < 4; e++){
      f[2*e]   = bf2f((unsigned short)(aw[e] & 0xFFFFu));
      f[2*e+1] = bf2f((unsigned short)(aw[e] >> 16));
    }
    f[0] += bf2f(cl[r0.x & 511]); f[1] += bf2f(cl[r0.y & 511]);
    f[2] += bf2f(cl[r0.z & 511]); f[3] += bf2f(cl[r0.w & 511]);
    f[4] += bf2f(cl[r1.x & 511]); f[5] += bf2f(cl[r1.y & 511]);
    f[6] += bf2f(cl[r1.z & 511]); f[7] += bf2f(cl[r1.w & 511]);
    int mm[8] = {m0.x, m0.y, m0.z, m0.w, m1.x, m1.y, m1.z, m1.w};
    float p[8];
    #pragma unroll
    for (int e = 0; e < 8; e++){
      p[e] = (mm[e] == 1) ? 0.0f : __expf(f[e]);
      se += p[e];
    }
    #pragma unroll
    for (int e = 0; e < 4; e++)
      aw[e] = (unsigned)f2bf(p[2*e]) | ((unsigned)f2bf(p[2*e+1]) << 16);
    *(uint4*)(srow + j) = make_uint4(aw[0], aw[1], aw[2], aw[3]);
  }
  se += __shfl_xor(se, 1);
  se += __shfl_xor(se, 2);
  se += __shfl_xor(se, 4);
  if ((l & 7) == 0) sumexp[(long)z * 1024 + i] = se;
}

extern "C" void kernel_launch(void* const* d_in, const int* in_sizes, int n_in,
                              void* d_out, int out_size, void* d_ws, size_t ws_size,
                              hipStream_t stream){
  (void)in_sizes; (void)n_in; (void)out_size; (void)ws_size;
  const float* query = (const float*)d_in[0];
  const float* key_  = (const float*)d_in[1];
  const float* value = (const float*)d_in[2];
  const float* rele  = (const float*)d_in[3];
  const int*   rel   = (const int*)d_in[4];
  const int*   mask  = (const int*)d_in[5];
  const float* Wq = (const float*)d_in[6];  const float* bq = (const float*)d_in[7];
  const float* Wk = (const float*)d_in[8];  const float* bk = (const float*)d_in[9];
  const float* Wv = (const float*)d_in[10]; const float* bv = (const float*)d_in[11];
  const float* Wo = (const float*)d_in[12]; const float* bo = (const float*)d_in[13];
  const float* Wlq = (const float*)d_in[14]; const float* blq = (const float*)d_in[15];
  const float* Wlk = (const float*)d_in[16]; const float* blk = (const float*)d_in[17];
  const float* Wtq = (const float*)d_in[18]; const float* btq = (const float*)d_in[19];
  const float* Wtk = (const float*)d_in[20]; const float* btk = (const float*)d_in[21];

  char* ws = (char*)d_ws;
  auto U = [&](size_t off){ return (unsigned short*)(ws + off); };
  // region 0..64MB: score S; convert staging + small weights + biasPack (all dead
  // before the score write) alias into it
  unsigned short* S    = U(0);
  unsigned short* qf   = U(0);          // A for merged QKV proj (qf|kf|vf contiguous)
  unsigned short* lt   = U(25165824);   // rel_emb bf16: l then t
  unsigned short* WqT  = U(27262976);   // WqT|WkT|WvT contiguous
  unsigned short* WlqT = U(33554432);
  unsigned short* WlkT = U(34603008);
  unsigned short* WtqT = U(35651584);
  unsigned short* WtkT = U(36700160);
  float*  biasPack     = (float*)(ws + 38797312);  // 12 KB, inside S region (dead by score)
  unsigned short* WoT  = U(67108864);
  unsigned short* qs   = U(69206016);   // scaled q [B,H,N,DK]; qs|kk|vv contiguous
  float*          sumexp = (float*)(ws + 69206016);  // aliases qs (dead after score+Cc), 128KB
  unsigned short* kk   = U(77594624);
  unsigned short* vv   = U(85983232);
  unsigned short* oh   = U(85983232);   // out_heads aliases vv (vv dead after vtrans)
  unsigned short* vT   = U(94371840);   // v^T [B,H,DK,N]
  unsigned short* lqs  = U(102760448);  // scaled lq [H,L,DK]
  unsigned short* lks  = U(103809024);  // lk [H,L,DK]
  unsigned short* Pt   = U(104857600);  // p2c table [B,H,N(j),L(r)]
  unsigned short* Cc   = U(138412032);  // c2p table [B,H,N(i),L(l)]

  const float invs = 1.0f / sqrtf(384.0f);  // 1/sqrt(3*DK)
  dim3 b256(256), b644(64, 4);

  // merged converts + bias pack
  k_convert4<<<2048, b256, 0, stream>>>(query, key_, value, rele, (ushort4*)ws,
                                        bq, bk, bv, biasPack);

  // merged weight transposes
  WtArgs wa;
  wa.W[0]=Wq;  wa.Wd[0]=WqT;           wa.N[0]=1024;
  wa.W[1]=Wk;  wa.Wd[1]=U(29360128);   wa.N[1]=1024;
  wa.W[2]=Wv;  wa.Wd[2]=U(31457280);   wa.N[2]=1024;
  wa.W[3]=Wo;  wa.Wd[3]=WoT;           wa.N[3]=1024;
  wa.W[4]=Wlq; wa.Wd[4]=WlqT;          wa.N[4]=512;
  wa.W[5]=Wlk; wa.Wd[5]=WlkT;          wa.N[5]=512;
  wa.W[6]=Wtq; wa.Wd[6]=WtqT;          wa.N[6]=512;
  wa.W[7]=Wtk; wa.Wd[7]=WtkT;          wa.N[7]=512;
  k_wtrans8<<<dim3(16,16,8), b644, 0, stream>>>(wa);

  // merged q/k/v projections: M=12288 (scale folded into q covers /sqrt(384) of c2c,c2p)
  k_gemm<6><<<dim3(8,96,1), b256, 0, stream>>>(qf,0, WqT,0,0, qs, biasPack, invs,
                                               12288,1024,1024, 10,0);

  // merged rel projections (scale folded into lq covers /sqrt(384) of p2c)
  RelArgs ra;
  ra.A[0]=lt;        ra.B[0]=WlqT; ra.C[0]=lqs; ra.bias[0]=blq; ra.scale[0]=invs; ra.hb[0]=0;
  ra.A[1]=lt+524288; ra.B[1]=WtqT; ra.C[1]=lqs; ra.bias[1]=btq; ra.scale[1]=invs; ra.hb[1]=4;
  ra.A[2]=lt;        ra.B[2]=WlkT; ra.C[2]=lks; ra.bias[2]=blk; ra.scale[2]=1.0f; ra.hb[2]=0;
  ra.A[3]=lt+524288; ra.B[3]=WtkT; ra.C[3]=lks; ra.bias[3]=btk; ra.scale[3]=1.0f; ra.hb[3]=4;
  k_relproj<<<dim3(4,4,4), b256, 0, stream>>>(ra);

  k_vtrans<<<dim3(2,16,32), b644, 0, stream>>>(vv, vT);

  // tables: Pt[z][j][r] = k_j . lq_r ; Cc[z][i][l] = q_i . lk_l
  k_gemm<0><<<dim3(4,8,32), b256, 0, stream>>>(kk,131072, lqs,65536,7, Pt, nullptr,1.0f, 1024,512,128, 0,0);
  k_gemm<0><<<dim3(4,8,32), b256, 0, stream>>>(qs,131072, lks,65536,7, Cc, nullptr,1.0f, 1024,512,128, 0,0);

  // fused score: c2c MFMA + p2c gather -> S (round-12 structure, depth-2 prefetch)
  k_scorep2c<<<dim3(32,32,2), b256, 0, stream>>>(qs, kk, Pt, rel, S);

  // S <- exp(S + c2p + mask) in place (no-max softmax numerator), row sums -> sumexp
  k_c2pexp<<<dim3(32,32), b256, 0, stream>>>(S, Cc, rel, mask, sumexp);

  // oh = (P @ v) / sumexp[row]   (64-row tiles -> 512 blocks = 2/CU)
  k_gemm64<5><<<dim3(1,16,32), b256, 0, stream>>>(S,1048576, vT,131072,-1, oh, sumexp, 1.0f, 1024,128,1024);

  // final: d_out = out_heads @ Wo + bo   (f32 out; 64-row tiles -> 512 blocks = 2/CU)
  k_gemm64<2><<<dim3(8,64,1), b256, 0, stream>>>(oh,0, WoT,0,0, d_out, bo, 1.0f, 4096,1024,1024);
}

// Round 17
// 337.947 us; speedup vs baseline: 1.2442x; 1.0062x over previous
//
#include <hip/hip_runtime.h>
#include <hip/hip_bf16.h>
#include <stdint.h>
#include <math.h>

// B=4, N=1024, D=1024, H=8, DK=128, L=512. All internal tensors bf16 in ws.
// GEMM convention everywhere: C[m,n] = sum_k A[m,k]*B[n,k]  (B stored [N,K]).

typedef __attribute__((ext_vector_type(8))) __bf16 bf16x8;
typedef __attribute__((ext_vector_type(4))) float f32x4;

#define DEV static __device__ __forceinline__

DEV float bf2f(unsigned short u){ union { unsigned int i; float f; } x; x.i = ((unsigned int)u) << 16; return x.f; }
DEV unsigned short f2bf(float f){ union { float f; unsigned int i; } x; x.f = f;
  unsigned int r = x.i + 0x7FFFu + ((x.i >> 16) & 1u); return (unsigned short)(r >> 16); }

#define GLDS16(gp, lp) __builtin_amdgcn_global_load_lds( \
    (const __attribute__((address_space(1))) void*)(gp), \
    (__attribute__((address_space(3))) void*)(lp), 16, 0, 0)

// ---------------- merged f32 -> bf16 convert: query,key,value,rel_emb + bias pack ----------------
__global__ __launch_bounds__(256) void k_convert4(const float* __restrict__ q,
    const float* __restrict__ k, const float* __restrict__ v,
    const float* __restrict__ r, ushort4* __restrict__ dst,
    const float* __restrict__ bq, const float* __restrict__ bk,
    const float* __restrict__ bv, float* __restrict__ biasPack){
  const int total = 3407872;   // 3*1048576 + 262144 float4 groups
  int gid = blockIdx.x * blockDim.x + threadIdx.x;
  if (gid < 3072)
    biasPack[gid] = (gid < 1024) ? bq[gid] : (gid < 2048 ? bk[gid - 1024] : bv[gid - 2048]);
  for (int i = gid; i < total; i += gridDim.x * blockDim.x){
    const float4* s;
    if (i < 2097152) s = (i < 1048576) ? ((const float4*)q + i) : ((const float4*)k + (i - 1048576));
    else             s = (i < 3145728) ? ((const float4*)v + (i - 2097152)) : ((const float4*)r + (i - 3145728));
    float4 x = *s;
    ushort4 o; o.x = f2bf(x.x); o.y = f2bf(x.y); o.z = f2bf(x.z); o.w = f2bf(x.w);
    dst[i] = o;
  }
}

// ---------------- merged weight transpose: 8 weights, W [1024,N] f32 -> WT [N,1024] bf16 ----
struct WtArgs { const float* W[8]; unsigned short* Wd[8]; int N[8]; };
__global__ __launch_bounds__(256) void k_wtrans8(WtArgs a){
  __shared__ unsigned short t[64][65];
  const int z = blockIdx.z, N = a.N[z];
  const int n0 = blockIdx.x * 64, k0 = blockIdx.y * 64;
  if (n0 >= N) return;
  const float* W = a.W[z];
  unsigned short* WT = a.Wd[z];
  int tx = threadIdx.x, ty = threadIdx.y;
  for (int r = ty; r < 64; r += 4) t[r][tx] = f2bf(W[(long)(k0 + r) * N + n0 + tx]);
  __syncthreads();
  for (int r = ty; r < 64; r += 4) WT[(long)(n0 + r) * 1024 + k0 + tx] = t[tx][r];
}

// ---------------- v [z][1024][128] -> vT [z][128][1024] (bf16) ----------------
__global__ __launch_bounds__(256) void k_vtrans(const unsigned short* __restrict__ V,
                                                unsigned short* __restrict__ VT){
  __shared__ unsigned short t[64][65];
  int z = blockIdx.z, d0 = blockIdx.x * 64, j0 = blockIdx.y * 64;
  int tx = threadIdx.x, ty = threadIdx.y;
  const unsigned short* v = V + (long)z * 131072;
  unsigned short* vt = VT + (long)z * 131072;
  for (int r = ty; r < 64; r += 4) t[r][tx] = v[(j0 + r) * 128 + d0 + tx];
  __syncthreads();
  for (int r = ty; r < 64; r += 4) vt[(d0 + r) * 1024 + j0 + tx] = t[tx][r];
}

// ---------------- GEMM: 128x128 tile, BK=32, 4 waves (2x2), m97 structure ----------------
// MODE 0: plain bf16 out [z][M][N]                       (tables)
// MODE 6: merged q/k/v projection: M=12288, B segment by m0>>12, packed bias,
//         scale only on segment 0, head-split remap into contiguous qs|kk|vv
template<int MODE>
__global__ __launch_bounds__(256) void k_gemm(
    const unsigned short* __restrict__ A, long sAz,
    const unsigned short* __restrict__ B, long sBz, int bzMask,
    void* __restrict__ Cout, const float* __restrict__ bias, float scale,
    int M, int N, int K, int logSeq, int headBase)
{
  __shared__ unsigned short Al[128 * 32];
  __shared__ unsigned short Bl[128 * 32];
  const int tid = threadIdx.x;
  const int lane = tid & 63, wave = tid >> 6;
  const int z = blockIdx.z;
  const int m0 = blockIdx.y * 128, n0 = blockIdx.x * 128;
  const unsigned short* Az = A + (long)z * sAz;
  const unsigned short* Bz = B + (long)(z & bzMask) * sBz;
  if constexpr (MODE == 6) Bz = B + (long)(m0 >> 12) * 1048576;
  const int lr = lane & 15, lk = lane >> 4;
  const int wr = wave >> 1, wc = wave & 1;

  f32x4 acc[4][4] = {};

  const unsigned short* ga = Az + (long)(m0 + (tid >> 2)) * K + (tid & 3) * 8;
  const unsigned short* gb = Bz + (long)(n0 + (tid >> 2)) * K + (tid & 3) * 8;
  unsigned short* lA = Al + wave * 512;
  unsigned short* lB = Bl + wave * 512;
  const long rowStep = (long)64 * K;

  for (int kt = 0; kt < K; kt += 32){
    GLDS16(ga + kt,           lA);
    GLDS16(ga + kt + rowStep, lA + 64 * 32);
    GLDS16(gb + kt,           lB);
    GLDS16(gb + kt + rowStep, lB + 64 * 32);
    __syncthreads();
    bf16x8 af[4], bfr[4];
    #pragma unroll
    for (int mi = 0; mi < 4; mi++) af[mi]  = *(const bf16x8*)&Al[(wr * 64 + mi * 16 + lr) * 32 + lk * 8];
    #pragma unroll
    for (int ni = 0; ni < 4; ni++) bfr[ni] = *(const bf16x8*)&Bl[(wc * 64 + ni * 16 + lr) * 32 + lk * 8];
    #pragma unroll
    for (int mi = 0; mi < 4; mi++)
      #pragma unroll
      for (int ni = 0; ni < 4; ni++)
        acc[mi][ni] = __builtin_amdgcn_mfma_f32_16x16x32_bf16(af[mi], bfr[ni], acc[mi][ni], 0, 0, 0);
    __syncthreads();
  }

  #pragma unroll
  for (int mi = 0; mi < 4; mi++){
    #pragma unroll
    for (int ni = 0; ni < 4; ni++){
      #pragma unroll
      for (int r = 0; r < 4; r++){
        const int row = m0 + wr * 64 + mi * 16 + (lane >> 4) * 4 + r;  // verified C layout
        const int col = n0 + wc * 64 + ni * 16 + (lane & 15);
        float v = acc[mi][ni][r];
        if constexpr (MODE == 0){
          ((unsigned short*)Cout)[(long)z * M * N + (long)row * N + col] = f2bf(v);
        } else { // MODE 6
          const int seg = row >> 12;
          float sc = (seg == 0) ? scale : 1.0f;
          v = (v + bias[(seg << 10) + col]) * sc;
          long idx = (((long)(row >> 10) * 8 + (col >> 7)) * 1024 + (row & 1023)) * 128 + (col & 127);
          ((unsigned short*)Cout)[idx] = f2bf(v);
        }
      }
    }
  }
}

// ---------------- GEMM64: 64x128 tile, BK=32, 4 waves (each 16 rows x 128 cols) ----------------
// MODE 2: f32 out [M][N], +bias       (final projection)
// MODE 5: bf16 out, acc/sumexp[z*1024+row], PV remap -> oh[b][i][h*128+dk]
template<int MODE>
__global__ __launch_bounds__(256) void k_gemm64(
    const unsigned short* __restrict__ A, long sAz,
    const unsigned short* __restrict__ B, long sBz, int bzMask,
    void* __restrict__ Cout, const float* __restrict__ bias, float scale,
    int M, int N, int K)
{
  __shared__ unsigned short Al[64 * 32];    // 4 KB
  __shared__ unsigned short Bl[128 * 32];   // 8 KB
  const int tid = threadIdx.x;
  const int lane = tid & 63, wave = tid >> 6;
  const int z = blockIdx.z;
  const int m0 = blockIdx.y * 64, n0 = blockIdx.x * 128;
  const unsigned short* Az = A + (long)z * sAz;
  const unsigned short* Bz = B + (long)(z & bzMask) * sBz;
  const int lr = lane & 15, lk = lane >> 4;

  f32x4 acc[8] = {};

  const unsigned short* ga = Az + (long)(m0 + (tid >> 2)) * K + (tid & 3) * 8;
  const unsigned short* gb = Bz + (long)(n0 + (tid >> 2)) * K + (tid & 3) * 8;
  unsigned short* lA = Al + wave * 512;
  unsigned short* lB = Bl + wave * 512;
  const long rowStep = (long)64 * K;

  for (int kt = 0; kt < K; kt += 32){
    GLDS16(ga + kt,           lA);
    GLDS16(gb + kt,           lB);
    GLDS16(gb + kt + rowStep, lB + 64 * 32);
    __syncthreads();
    bf16x8 af = *(const bf16x8*)&Al[(wave * 16 + lr) * 32 + lk * 8];
    #pragma unroll
    for (int ni = 0; ni < 8; ni++){
      bf16x8 bfr = *(const bf16x8*)&Bl[(ni * 16 + lr) * 32 + lk * 8];
      acc[ni] = __builtin_amdgcn_mfma_f32_16x16x32_bf16(af, bfr, acc[ni], 0, 0, 0);
    }
    __syncthreads();
  }

  #pragma unroll
  for (int ni = 0; ni < 8; ni++){
    #pragma unroll
    for (int r = 0; r < 4; r++){
      const int row = m0 + wave * 16 + (lane >> 4) * 4 + r;  // verified C layout
      const int col = n0 + ni * 16 + (lane & 15);
      float v = acc[ni][r];
      if constexpr (MODE == 2){
        ((float*)Cout)[(long)row * N + col] = v + bias[col];
      } else { // MODE 5: PV normalize + remap
        float se = bias[(long)z * 1024 + row];
        v = v / se;
        ((unsigned short*)Cout)[((long)(z >> 3) * 1024 + row) * 1024 + (z & 7) * 128 + col] = f2bf(v);
      }
    }
  }
}

// ---------------- merged rel projections: 4 (A,B,C,bias,scale,headBase) sets ----------------
struct RelArgs { const unsigned short* A[4]; const unsigned short* B[4];
                 unsigned short* C[4]; const float* bias[4]; float scale[4]; int hb[4]; };
__global__ __launch_bounds__(256) void k_relproj(RelArgs a){
  __shared__ unsigned short Al[128 * 32];
  __shared__ unsigned short Bl[128 * 32];
  const int tid = threadIdx.x;
  const int lane = tid & 63, wave = tid >> 6;
  const int z = blockIdx.z;   // which projection
  const int m0 = blockIdx.y * 128, n0 = blockIdx.x * 128;
  const int lr = lane & 15, lk = lane >> 4;
  const int wr = wave >> 1, wc = wave & 1;
  const int K = 1024;

  f32x4 acc[4][4] = {};
  const unsigned short* ga = a.A[z] + (long)(m0 + (tid >> 2)) * K + (tid & 3) * 8;
  const unsigned short* gb = a.B[z] + (long)(n0 + (tid >> 2)) * K + (tid & 3) * 8;
  unsigned short* lA = Al + wave * 512;
  unsigned short* lB = Bl + wave * 512;
  const long rowStep = (long)64 * K;

  for (int kt = 0; kt < K; kt += 32){
    GLDS16(ga + kt,           lA);
    GLDS16(ga + kt + rowStep, lA + 64 * 32);
    GLDS16(gb + kt,           lB);
    GLDS16(gb + kt + rowStep, lB + 64 * 32);
    __syncthreads();
    bf16x8 af[4], bfr[4];
    #pragma unroll
    for (int mi = 0; mi < 4; mi++) af[mi]  = *(const bf16x8*)&Al[(wr * 64 + mi * 16 + lr) * 32 + lk * 8];
    #pragma unroll
    for (int ni = 0; ni < 4; ni++) bfr[ni] = *(const bf16x8*)&Bl[(wc * 64 + ni * 16 + lr) * 32 + lk * 8];
    #pragma unroll
    for (int mi = 0; mi < 4; mi++)
      #pragma unroll
      for (int ni = 0; ni < 4; ni++)
        acc[mi][ni] = __builtin_amdgcn_mfma_f32_16x16x32_bf16(af[mi], bfr[ni], acc[mi][ni], 0, 0, 0);
    __syncthreads();
  }

  const float scl = a.scale[z];
  const float* bias = a.bias[z];
  unsigned short* C = a.C[z];
  const int hb = a.hb[z];
  #pragma unroll
  for (int mi = 0; mi < 4; mi++){
    #pragma unroll
    for (int ni = 0; ni < 4; ni++){
      #pragma unroll
      for (int r = 0; r < 4; r++){
        const int row = m0 + wr * 64 + mi * 16 + (lane >> 4) * 4 + r;
        const int col = n0 + wc * 64 + ni * 16 + (lane & 15);
        float v = (acc[mi][ni][r] + bias[col]) * scl;
        long idx = (((long)(hb + (col >> 7))) * 512 + row) * 128 + (col & 127);
        C[idx] = f2bf(v);
      }
    }
  }
}

// ---------------- fused score: S[z][i][j] = c2c(q.k) + p2c gather (one S write) ----------------
// Round-12 structure, depth-2 prefetch, strip loop FULLY UNROLLED: the explicit register
// rotation (rv0=rv1 etc.) was a v_mov from pending-load destinations, forcing vmcnt waits
// at end of each strip (round-16 post-mortem: VALUBusy +8%, duration flat). Full unroll
// lets copy-propagation delete the rotations so the s+1/s+2 loads genuinely stay in
// flight across the raw barriers (lgkmcnt-only wait keeps vmcnt untouched).
__global__ __launch_bounds__(256) void k_scorep2c(
    const unsigned short* __restrict__ qs, const unsigned short* __restrict__ kk,
    const unsigned short* __restrict__ Pt, const int* __restrict__ rel,
    unsigned short* __restrict__ S)
{
  __shared__ unsigned short Ptl[32][512];      // 32 KB
  __shared__ unsigned short T[2][32][66];      // p2c exchange, double-buffered
  __shared__ unsigned short Tc[4][16][40];     // c2c exchange per wave (same-wave only)
  const int tid = threadIdx.x, l = tid & 63, w = tid >> 6;
  const int j0 = blockIdx.x * 32, z = blockIdx.y, ih = blockIdx.z;
  const long zb = (long)z << 20;
  const int lr = l & 15, lk = l >> 4;

  { // stage Pt rows (32 x 1KB, linear)
    const char* g = (const char*)(Pt + ((long)z * 1024 + j0) * 512);
    char* lb = (char*)&Ptl[0][0];
    #pragma unroll
    for (int it = 0; it < 8; it++)
      GLDS16(g + it * 4096 + w * 1024 + l * 16, lb + it * 4096 + w * 1024);
  }

  // k fragments: direct global->register, invariant across strips
  const unsigned short* kz = kk + (long)z * 131072;
  bf16x8 kf[4][2];
  #pragma unroll
  for (int kt = 0; kt < 4; kt++)
    #pragma unroll
    for (int ni = 0; ni < 2; ni++)
      kf[kt][ni] = *(const bf16x8*)&kz[(j0 + ni * 16 + lr) * 128 + kt * 32 + lk * 8];

  const int jb = w * 8;               // gather-phase j-rows for this wave
  const int il = tid >> 2;            // add-phase strip-local i (0..63)
  const int jq = (tid & 3) * 8;       // add-phase j-quarter
  const unsigned short* qz = qs + (long)z * 131072;
  const int* relb = rel + zb + (long)(j0 + jb) * 1024 + l;

  // prologue: prefetch strips 0 and 1
  int rv0[8], rv1[8]; bf16x8 af0[4], af1[4];
  {
    const int ia = ih * 512, ib2 = ia + 64;
    #pragma unroll
    for (int jj = 0; jj < 8; jj++) rv0[jj] = relb[jj * 1024 + ia];
    #pragma unroll
    for (int kt = 0; kt < 4; kt++)
      af0[kt] = *(const bf16x8*)&qz[(ia + w * 16 + lr) * 128 + kt * 32 + lk * 8];
    #pragma unroll
    for (int jj = 0; jj < 8; jj++) rv1[jj] = relb[jj * 1024 + ib2];
    #pragma unroll
    for (int kt = 0; kt < 4; kt++)
      af1[kt] = *(const bf16x8*)&qz[(ib2 + w * 16 + lr) * 128 + kt * 32 + lk * 8];
  }
  __syncthreads();   // Ptl staged (full drain here is fine: once per block)

  #pragma unroll
  for (int s = 0; s < 8; s++){
    const int i0 = ih * 512 + s * 64;
    const int tb = s & 1;
    // gather phase (uses strip-s prefetch rv0)
    unsigned short vals[8];
    #pragma unroll
    for (int jj = 0; jj < 8; jj++) vals[jj] = Ptl[jb + jj][rv0[jj] & 511];
    #pragma unroll
    for (int jj = 0; jj < 8; jj++) T[tb][jb + jj][l] = vals[jj];
    // prefetch strip s+2 (stays in flight across barriers)
    int rvn[8] = {}; bf16x8 afn[4] = {};
    if (s < 6){
      const int i2 = i0 + 128;
      #pragma unroll
      for (int jj = 0; jj < 8; jj++) rvn[jj] = relb[jj * 1024 + i2];
      #pragma unroll
      for (int kt = 0; kt < 4; kt++)
        afn[kt] = *(const bf16x8*)&qz[(i2 + w * 16 + lr) * 128 + kt * 32 + lk * 8];
    }
    asm volatile("s_waitcnt lgkmcnt(0)" ::: "memory");  // T writes visible; vmcnt untouched
    __builtin_amdgcn_s_barrier();
    __builtin_amdgcn_sched_barrier(0);                  // rule #18: pin ordering after raw barrier

    // compute phase: wave w computes strip rows w*16..w*16+16 x 32 j
    f32x4 acc0 = {}, acc1 = {};
    #pragma unroll
    for (int kt = 0; kt < 4; kt++){
      acc0 = __builtin_amdgcn_mfma_f32_16x16x32_bf16(af0[kt], kf[kt][0], acc0, 0, 0, 0);
      acc1 = __builtin_amdgcn_mfma_f32_16x16x32_bf16(af0[kt], kf[kt][1], acc1, 0, 0, 0);
    }
    #pragma unroll
    for (int r = 0; r < 4; r++){
      Tc[w][lk * 4 + r][lr]      = f2bf(acc0[r]);
      Tc[w][lk * 4 + r][16 + lr] = f2bf(acc1[r]);
    }
    // same-wave LDS dependency (compiler inserts lgkmcnt); T cross-wave covered by barrier
    float f[8];
    #pragma unroll
    for (int jj = 0; jj < 8; jj++)
      f[jj] = bf2f(Tc[w][l >> 2][jq + jj]) + bf2f(T[tb][jq + jj][il]);
    unsigned int aw[4];
    #pragma unroll
    for (int e = 0; e < 4; e++)
      aw[e] = (unsigned)f2bf(f[2*e]) | ((unsigned)f2bf(f[2*e+1]) << 16);
    *(uint4*)(S + zb + (long)(i0 + il) * 1024 + j0 + jq) = make_uint4(aw[0], aw[1], aw[2], aw[3]);

    // rotate prefetch registers (copy-propagated away by the full unroll)
    #pragma unroll
    for (int jj = 0; jj < 8; jj++){ rv0[jj] = rv1[jj]; rv1[jj] = rvn[jj]; }
    #pragma unroll
    for (int kt = 0; kt < 4; kt++){ af0[kt] = af1[kt]; af1[kt] = afn[kt]; }
  }
}

// ---------------- c2p + mask + exp (no-max softmax numerator) + row expsum ----------------
__global__ __launch_bounds__(256) void k_c2pexp(unsigned short* __restrict__ S,
    const unsigned short* __restrict__ Cc, const int* __restrict__ rel,
    const int* __restrict__ maskp, float* __restrict__ sumexp){
  __shared__ unsigned short Ccl[32][512];   // 32 KB
  const int tid = threadIdx.x, l = tid & 63, w = tid >> 6;
  const int z = blockIdx.y, i0 = blockIdx.x * 32;
  const long zb = (long)z << 20;
  {
    const char* g = (const char*)Cc + ((long)z * 1024 + i0) * 1024;  // 32 rows x 1KB
    char* lb = (char*)&Ccl[0][0];
    #pragma unroll
    for (int it = 0; it < 8; it++)
      GLDS16(g + it * 4096 + w * 1024 + l * 16, lb + it * 4096 + w * 1024);
  }
  __syncthreads();
  const int il = tid >> 3;            // row 0..31
  const int jq = (tid & 7) * 8;       // j offset within 64-strip
  const int i = i0 + il;
  unsigned short* srow = S + zb + (long)i * 1024;
  const int* relrow  = rel + zb + (long)i * 1024;
  const int* maskrow = maskp + (((long)(z >> 3)) << 20) + (long)i * 1024;
  const unsigned short* cl = &Ccl[il][0];
  float se = 0.f;
  for (int j0 = 0; j0 < 1024; j0 += 64){
    const int j = j0 + jq;
    uint4 a = *(const uint4*)(srow + j);
    int4 r0 = ((const int4*)(relrow + j))[0];
    int4 r1 = ((const int4*)(relrow + j))[1];
    int4 m0 = ((const int4*)(maskrow + j))[0];
    int4 m1 = ((const int4*)(maskrow + j))[1];
    unsigned int aw[4] = {a.x, a.y, a.z, a.w};
    float f[8];
    #pragma unroll
    for (int e = 0; e < 4; e++){
      f[2*e]   = bf2f((unsigned short)(aw[e] & 0xFFFFu));
      f[2*e+1] = bf2f((unsigned short)(aw[e] >> 16));
    }
    f[0] += bf2f(cl[r0.x & 511]); f[1] += bf2f(cl[r0.y & 511]);
    f[2] += bf2f(cl[r0.z & 511]); f[3] += bf2f(cl[r0.w & 511]);
    f[4] += bf2f(cl[r1.x & 511]); f[5] += bf2f(cl[r1.y & 511]);
    f[6] += bf2f(cl[r1.z & 511]); f[7] += bf2f(cl[r1.w & 511]);
    int mm[8] = {m0.x, m0.y, m0.z, m0.w, m1.x, m1.y, m1.z, m1.w};
    float p[8];
    #pragma unroll
    for (int e = 0; e < 8; e++){
      p[e] = (mm[e] == 1) ? 0.0f : __expf(f[e]);
      se += p[e];
    }
    #pragma unroll
    for (int e = 0; e < 4; e++)
      aw[e] = (unsigned)f2bf(p[2*e]) | ((unsigned)f2bf(p[2*e+1]) << 16);
    *(uint4*)(srow + j) = make_uint4(aw[0], aw[1], aw[2], aw[3]);
  }
  se += __shfl_xor(se, 1);
  se += __shfl_xor(se, 2);
  se += __shfl_xor(se, 4);
  if ((l & 7) == 0) sumexp[(long)z * 1024 + i] = se;
}

extern "C" void kernel_launch(void* const* d_in, const int* in_sizes, int n_in,
                              void* d_out, int out_size, void* d_ws, size_t ws_size,
                              hipStream_t stream){
  (void)in_sizes; (void)n_in; (void)out_size; (void)ws_size;
  const float* query = (const float*)d_in[0];
  const float* key_  = (const float*)d_in[1];
  const float* value = (const float*)d_in[2];
  const float* rele  = (const float*)d_in[3];
  const int*   rel   = (const int*)d_in[4];
  const int*   mask  = (const int*)d_in[5];
  const float* Wq = (const float*)d_in[6];  const float* bq = (const float*)d_in[7];
  const float* Wk = (const float*)d_in[8];  const float* bk = (const float*)d_in[9];
  const float* Wv = (const float*)d_in[10]; const float* bv = (const float*)d_in[11];
  const float* Wo = (const float*)d_in[12]; const float* bo = (const float*)d_in[13];
  const float* Wlq = (const float*)d_in[14]; const float* blq = (const float*)d_in[15];
  const float* Wlk = (const float*)d_in[16]; const float* blk = (const float*)d_in[17];
  const float* Wtq = (const float*)d_in[18]; const float* btq = (const float*)d_in[19];
  const float* Wtk = (const float*)d_in[20]; const float* btk = (const float*)d_in[21];

  char* ws = (char*)d_ws;
  auto U = [&](size_t off){ return (unsigned short*)(ws + off); };
  // region 0..64MB: score S; convert staging + small weights + biasPack (all dead
  // before the score write) alias into it
  unsigned short* S    = U(0);
  unsigned short* qf   = U(0);          // A for merged QKV proj (qf|kf|vf contiguous)
  unsigned short* lt   = U(25165824);   // rel_emb bf16: l then t
  unsigned short* WqT  = U(27262976);   // WqT|WkT|WvT contiguous
  unsigned short* WlqT = U(33554432);
  unsigned short* WlkT = U(34603008);
  unsigned short* WtqT = U(35651584);
  unsigned short* WtkT = U(36700160);
  float*  biasPack     = (float*)(ws + 38797312);  // 12 KB, inside S region (dead by score)
  unsigned short* WoT  = U(67108864);
  unsigned short* qs   = U(69206016);   // scaled q [B,H,N,DK]; qs|kk|vv contiguous
  float*          sumexp = (float*)(ws + 69206016);  // aliases qs (dead after score+Cc), 128KB
  unsigned short* kk   = U(77594624);
  unsigned short* vv   = U(85983232);
  unsigned short* oh   = U(85983232);   // out_heads aliases vv (vv dead after vtrans)
  unsigned short* vT   = U(94371840);   // v^T [B,H,DK,N]
  unsigned short* lqs  = U(102760448);  // scaled lq [H,L,DK]
  unsigned short* lks  = U(103809024);  // lk [H,L,DK]
  unsigned short* Pt   = U(104857600);  // p2c table [B,H,N(j),L(r)]
  unsigned short* Cc   = U(138412032);  // c2p table [B,H,N(i),L(l)]

  const float invs = 1.0f / sqrtf(384.0f);  // 1/sqrt(3*DK)
  dim3 b256(256), b644(64, 4);

  // merged converts + bias pack
  k_convert4<<<2048, b256, 0, stream>>>(query, key_, value, rele, (ushort4*)ws,
                                        bq, bk, bv, biasPack);

  // merged weight transposes
  WtArgs wa;
  wa.W[0]=Wq;  wa.Wd[0]=WqT;           wa.N[0]=1024;
  wa.W[1]=Wk;  wa.Wd[1]=U(29360128);   wa.N[1]=1024;
  wa.W[2]=Wv;  wa.Wd[2]=U(31457280);   wa.N[2]=1024;
  wa.W[3]=Wo;  wa.Wd[3]=WoT;           wa.N[3]=1024;
  wa.W[4]=Wlq; wa.Wd[4]=WlqT;          wa.N[4]=512;
  wa.W[5]=Wlk; wa.Wd[5]=WlkT;          wa.N[5]=512;
  wa.W[6]=Wtq; wa.Wd[6]=WtqT;          wa.N[6]=512;
  wa.W[7]=Wtk; wa.Wd[7]=WtkT;          wa.N[7]=512;
  k_wtrans8<<<dim3(16,16,8), b644, 0, stream>>>(wa);

  // merged q/k/v projections: M=12288 (scale folded into q covers /sqrt(384) of c2c,c2p)
  k_gemm<6><<<dim3(8,96,1), b256, 0, stream>>>(qf,0, WqT,0,0, qs, biasPack, invs,
                                               12288,1024,1024, 10,0);

  // merged rel projections (scale folded into lq covers /sqrt(384) of p2c)
  RelArgs ra;
  ra.A[0]=lt;        ra.B[0]=WlqT; ra.C[0]=lqs; ra.bias[0]=blq; ra.scale[0]=invs; ra.hb[0]=0;
  ra.A[1]=lt+524288; ra.B[1]=WtqT; ra.C[1]=lqs; ra.bias[1]=btq; ra.scale[1]=invs; ra.hb[1]=4;
  ra.A[2]=lt;        ra.B[2]=WlkT; ra.C[2]=lks; ra.bias[2]=blk; ra.scale[2]=1.0f; ra.hb[2]=0;
  ra.A[3]=lt+524288; ra.B[3]=WtkT; ra.C[3]=lks; ra.bias[3]=btk; ra.scale[3]=1.0f; ra.hb[3]=4;
  k_relproj<<<dim3(4,4,4), b256, 0, stream>>>(ra);

  k_vtrans<<<dim3(2,16,32), b644, 0, stream>>>(vv, vT);

  // tables: Pt[z][j][r] = k_j . lq_r ; Cc[z][i][l] = q_i . lk_l
  k_gemm<0><<<dim3(4,8,32), b256, 0, stream>>>(kk,131072, lqs,65536,7, Pt, nullptr,1.0f, 1024,512,128, 0,0);
  k_gemm<0><<<dim3(4,8,32), b256, 0, stream>>>(qs,131072, lks,65536,7, Cc, nullptr,1.0f, 1024,512,128, 0,0);

  // fused score: c2c MFMA + p2c gather -> S (depth-2 prefetch, fully unrolled strips)
  k_scorep2c<<<dim3(32,32,2), b256, 0, stream>>>(qs, kk, Pt, rel, S);

  // S <- exp(S + c2p + mask) in place (no-max softmax numerator), row sums -> sumexp
  k_c2pexp<<<dim3(32,32), b256, 0, stream>>>(S, Cc, rel, mask, sumexp);

  // oh = (P @ v) / sumexp[row]   (64-row tiles -> 512 blocks = 2/CU)
  k_gemm64<5><<<dim3(1,16,32), b256, 0, stream>>>(S,1048576, vT,131072,-1, oh, sumexp, 1.0f, 1024,128,1024);

  // final: d_out = out_heads @ Wo + bo   (f32 out; 64-row tiles -> 512 blocks = 2/CU)
  k_gemm64<2><<<dim3(8,64,1), b256, 0, stream>>>(oh,0, WoT,0,0, d_out, bo, 1.0f, 4096,1024,1024);
}

// Round 18
// 335.127 us; speedup vs baseline: 1.2547x; 1.0084x over previous
//
#include <hip/hip_runtime.h>
#include <hip/hip_bf16.h>
#include <stdint.h>
#include <math.h>

// B=4, N=1024, D=1024, H=8, DK=128, L=512. All internal tensors bf16 in ws.
// GEMM convention everywhere: C[m,n] = sum_k A[m,k]*B[n,k]  (B stored [N,K]).

typedef __attribute__((ext_vector_type(8))) __bf16 bf16x8;
typedef __attribute__((ext_vector_type(4))) float f32x4;

#define DEV static __device__ __forceinline__

DEV float bf2f(unsigned short u){ union { unsigned int i; float f; } x; x.i = ((unsigned int)u) << 16; return x.f; }
DEV unsigned short f2bf(float f){ union { float f; unsigned int i; } x; x.f = f;
  unsigned int r = x.i + 0x7FFFu + ((x.i >> 16) & 1u); return (unsigned short)(r >> 16); }

#define GLDS16(gp, lp) __builtin_amdgcn_global_load_lds( \
    (const __attribute__((address_space(1))) void*)(gp), \
    (__attribute__((address_space(3))) void*)(lp), 16, 0, 0)

// ---------------- merged f32 -> bf16 convert: query,key,value,rel_emb + bias pack ----------------
__global__ __launch_bounds__(256) void k_convert4(const float* __restrict__ q,
    const float* __restrict__ k, const float* __restrict__ v,
    const float* __restrict__ r, ushort4* __restrict__ dst,
    const float* __restrict__ bq, const float* __restrict__ bk,
    const float* __restrict__ bv, float* __restrict__ biasPack){
  const int total = 3407872;   // 3*1048576 + 262144 float4 groups
  int gid = blockIdx.x * blockDim.x + threadIdx.x;
  if (gid < 3072)
    biasPack[gid] = (gid < 1024) ? bq[gid] : (gid < 2048 ? bk[gid - 1024] : bv[gid - 2048]);
  for (int i = gid; i < total; i += gridDim.x * blockDim.x){
    const float4* s;
    if (i < 2097152) s = (i < 1048576) ? ((const float4*)q + i) : ((const float4*)k + (i - 1048576));
    else             s = (i < 3145728) ? ((const float4*)v + (i - 2097152)) : ((const float4*)r + (i - 3145728));
    float4 x = *s;
    ushort4 o; o.x = f2bf(x.x); o.y = f2bf(x.y); o.z = f2bf(x.z); o.w = f2bf(x.w);
    dst[i] = o;
  }
}

// ---------------- merged weight transpose: 8 weights, W [1024,N] f32 -> WT [N,1024] bf16 ----
struct WtArgs { const float* W[8]; unsigned short* Wd[8]; int N[8]; };
__global__ __launch_bounds__(256) void k_wtrans8(WtArgs a){
  __shared__ unsigned short t[64][65];
  const int z = blockIdx.z, N = a.N[z];
  const int n0 = blockIdx.x * 64, k0 = blockIdx.y * 64;
  if (n0 >= N) return;
  const float* W = a.W[z];
  unsigned short* WT = a.Wd[z];
  int tx = threadIdx.x, ty = threadIdx.y;
  for (int r = ty; r < 64; r += 4) t[r][tx] = f2bf(W[(long)(k0 + r) * N + n0 + tx]);
  __syncthreads();
  for (int r = ty; r < 64; r += 4) WT[(long)(n0 + r) * 1024 + k0 + tx] = t[tx][r];
}

// ---------------- v [z][1024][128] -> vT [z][128][1024] (bf16) ----------------
__global__ __launch_bounds__(256) void k_vtrans(const unsigned short* __restrict__ V,
                                                unsigned short* __restrict__ VT){
  __shared__ unsigned short t[64][65];
  int z = blockIdx.z, d0 = blockIdx.x * 64, j0 = blockIdx.y * 64;
  int tx = threadIdx.x, ty = threadIdx.y;
  const unsigned short* v = V + (long)z * 131072;
  unsigned short* vt = VT + (long)z * 131072;
  for (int r = ty; r < 64; r += 4) t[r][tx] = v[(j0 + r) * 128 + d0 + tx];
  __syncthreads();
  for (int r = ty; r < 64; r += 4) vt[(d0 + r) * 1024 + j0 + tx] = t[tx][r];
}

// ---------------- GEMM: 128x128 tile, BK=32, 4 waves (2x2), m97 structure ----------------
// MODE 0: plain bf16 out [z][M][N]                       (tables)
// MODE 6: merged q/k/v projection: M=12288, B segment by m0>>12, packed bias,
//         scale only on segment 0, head-split remap into contiguous qs|kk|vv
template<int MODE>
__global__ __launch_bounds__(256) void k_gemm(
    const unsigned short* __restrict__ A, long sAz,
    const unsigned short* __restrict__ B, long sBz, int bzMask,
    void* __restrict__ Cout, const float* __restrict__ bias, float scale,
    int M, int N, int K, int logSeq, int headBase)
{
  __shared__ unsigned short Al[128 * 32];
  __shared__ unsigned short Bl[128 * 32];
  const int tid = threadIdx.x;
  const int lane = tid & 63, wave = tid >> 6;
  const int z = blockIdx.z;
  const int m0 = blockIdx.y * 128, n0 = blockIdx.x * 128;
  const unsigned short* Az = A + (long)z * sAz;
  const unsigned short* Bz = B + (long)(z & bzMask) * sBz;
  if constexpr (MODE == 6) Bz = B + (long)(m0 >> 12) * 1048576;
  const int lr = lane & 15, lk = lane >> 4;
  const int wr = wave >> 1, wc = wave & 1;

  f32x4 acc[4][4] = {};

  const unsigned short* ga = Az + (long)(m0 + (tid >> 2)) * K + (tid & 3) * 8;
  const unsigned short* gb = Bz + (long)(n0 + (tid >> 2)) * K + (tid & 3) * 8;
  unsigned short* lA = Al + wave * 512;
  unsigned short* lB = Bl + wave * 512;
  const long rowStep = (long)64 * K;

  for (int kt = 0; kt < K; kt += 32){
    GLDS16(ga + kt,           lA);
    GLDS16(ga + kt + rowStep, lA + 64 * 32);
    GLDS16(gb + kt,           lB);
    GLDS16(gb + kt + rowStep, lB + 64 * 32);
    __syncthreads();
    bf16x8 af[4], bfr[4];
    #pragma unroll
    for (int mi = 0; mi < 4; mi++) af[mi]  = *(const bf16x8*)&Al[(wr * 64 + mi * 16 + lr) * 32 + lk * 8];
    #pragma unroll
    for (int ni = 0; ni < 4; ni++) bfr[ni] = *(const bf16x8*)&Bl[(wc * 64 + ni * 16 + lr) * 32 + lk * 8];
    #pragma unroll
    for (int mi = 0; mi < 4; mi++)
      #pragma unroll
      for (int ni = 0; ni < 4; ni++)
        acc[mi][ni] = __builtin_amdgcn_mfma_f32_16x16x32_bf16(af[mi], bfr[ni], acc[mi][ni], 0, 0, 0);
    __syncthreads();
  }

  #pragma unroll
  for (int mi = 0; mi < 4; mi++){
    #pragma unroll
    for (int ni = 0; ni < 4; ni++){
      #pragma unroll
      for (int r = 0; r < 4; r++){
        const int row = m0 + wr * 64 + mi * 16 + (lane >> 4) * 4 + r;  // verified C layout
        const int col = n0 + wc * 64 + ni * 16 + (lane & 15);
        float v = acc[mi][ni][r];
        if constexpr (MODE == 0){
          ((unsigned short*)Cout)[(long)z * M * N + (long)row * N + col] = f2bf(v);
        } else { // MODE 6
          const int seg = row >> 12;
          float sc = (seg == 0) ? scale : 1.0f;
          v = (v + bias[(seg << 10) + col]) * sc;
          long idx = (((long)(row >> 10) * 8 + (col >> 7)) * 1024 + (row & 1023)) * 128 + (col & 127);
          ((unsigned short*)Cout)[idx] = f2bf(v);
        }
      }
    }
  }
}

// ---------------- GEMM64: 64x128 tile, BK=32, 4 waves (each 16 rows x 128 cols) ----------------
// MODE 2: f32 out [M][N], +bias       (final projection)
template<int MODE>
__global__ __launch_bounds__(256) void k_gemm64(
    const unsigned short* __restrict__ A, long sAz,
    const unsigned short* __restrict__ B, long sBz, int bzMask,
    void* __restrict__ Cout, const float* __restrict__ bias, float scale,
    int M, int N, int K)
{
  __shared__ unsigned short Al[64 * 32];    // 4 KB
  __shared__ unsigned short Bl[128 * 32];   // 8 KB
  const int tid = threadIdx.x;
  const int lane = tid & 63, wave = tid >> 6;
  const int z = blockIdx.z;
  const int m0 = blockIdx.y * 64, n0 = blockIdx.x * 128;
  const unsigned short* Az = A + (long)z * sAz;
  const unsigned short* Bz = B + (long)(z & bzMask) * sBz;
  const int lr = lane & 15, lk = lane >> 4;

  f32x4 acc[8] = {};

  const unsigned short* ga = Az + (long)(m0 + (tid >> 2)) * K + (tid & 3) * 8;
  const unsigned short* gb = Bz + (long)(n0 + (tid >> 2)) * K + (tid & 3) * 8;
  unsigned short* lA = Al + wave * 512;
  unsigned short* lB = Bl + wave * 512;
  const long rowStep = (long)64 * K;

  for (int kt = 0; kt < K; kt += 32){
    GLDS16(ga + kt,           lA);
    GLDS16(gb + kt,           lB);
    GLDS16(gb + kt + rowStep, lB + 64 * 32);
    __syncthreads();
    bf16x8 af = *(const bf16x8*)&Al[(wave * 16 + lr) * 32 + lk * 8];
    #pragma unroll
    for (int ni = 0; ni < 8; ni++){
      bf16x8 bfr = *(const bf16x8*)&Bl[(ni * 16 + lr) * 32 + lk * 8];
      acc[ni] = __builtin_amdgcn_mfma_f32_16x16x32_bf16(af, bfr, acc[ni], 0, 0, 0);
    }
    __syncthreads();
  }

  #pragma unroll
  for (int ni = 0; ni < 8; ni++){
    #pragma unroll
    for (int r = 0; r < 4; r++){
      const int row = m0 + wave * 16 + (lane >> 4) * 4 + r;  // verified C layout
      const int col = n0 + ni * 16 + (lane & 15);
      ((float*)Cout)[(long)row * N + col] = acc[ni][r] + bias[col];
    }
  }
}

// ---------------- merged rel projections: 4 (A,B,C,bias,scale,headBase) sets ----------------
struct RelArgs { const unsigned short* A[4]; const unsigned short* B[4];
                 unsigned short* C[4]; const float* bias[4]; float scale[4]; int hb[4]; };
__global__ __launch_bounds__(256) void k_relproj(RelArgs a){
  __shared__ unsigned short Al[128 * 32];
  __shared__ unsigned short Bl[128 * 32];
  const int tid = threadIdx.x;
  const int lane = tid & 63, wave = tid >> 6;
  const int z = blockIdx.z;   // which projection
  const int m0 = blockIdx.y * 128, n0 = blockIdx.x * 128;
  const int lr = lane & 15, lk = lane >> 4;
  const int wr = wave >> 1, wc = wave & 1;
  const int K = 1024;

  f32x4 acc[4][4] = {};
  const unsigned short* ga = a.A[z] + (long)(m0 + (tid >> 2)) * K + (tid & 3) * 8;
  const unsigned short* gb = a.B[z] + (long)(n0 + (tid >> 2)) * K + (tid & 3) * 8;
  unsigned short* lA = Al + wave * 512;
  unsigned short* lB = Bl + wave * 512;
  const long rowStep = (long)64 * K;

  for (int kt = 0; kt < K; kt += 32){
    GLDS16(ga + kt,           lA);
    GLDS16(ga + kt + rowStep, lA + 64 * 32);
    GLDS16(gb + kt,           lB);
    GLDS16(gb + kt + rowStep, lB + 64 * 32);
    __syncthreads();
    bf16x8 af[4], bfr[4];
    #pragma unroll
    for (int mi = 0; mi < 4; mi++) af[mi]  = *(const bf16x8*)&Al[(wr * 64 + mi * 16 + lr) * 32 + lk * 8];
    #pragma unroll
    for (int ni = 0; ni < 4; ni++) bfr[ni] = *(const bf16x8*)&Bl[(wc * 64 + ni * 16 + lr) * 32 + lk * 8];
    #pragma unroll
    for (int mi = 0; mi < 4; mi++)
      #pragma unroll
      for (int ni = 0; ni < 4; ni++)
        acc[mi][ni] = __builtin_amdgcn_mfma_f32_16x16x32_bf16(af[mi], bfr[ni], acc[mi][ni], 0, 0, 0);
    __syncthreads();
  }

  const float scl = a.scale[z];
  const float* bias = a.bias[z];
  unsigned short* C = a.C[z];
  const int hb = a.hb[z];
  #pragma unroll
  for (int mi = 0; mi < 4; mi++){
    #pragma unroll
    for (int ni = 0; ni < 4; ni++){
      #pragma unroll
      for (int r = 0; r < 4; r++){
        const int row = m0 + wr * 64 + mi * 16 + (lane >> 4) * 4 + r;
        const int col = n0 + wc * 64 + ni * 16 + (lane & 15);
        float v = (acc[mi][ni][r] + bias[col]) * scl;
        long idx = (((long)(hb + (col >> 7))) * 512 + row) * 128 + (col & 127);
        C[idx] = f2bf(v);
      }
    }
  }
}

// ---------------- fused score: S[z][i][j] = c2c(q.k) + p2c gather (one S write) ----------------
// Round-12 structure, depth-2 prefetch, fully unrolled strips (round-17 variant, ~89 us;
// plateau accepted after 5 structurally different attempts all landed at ~90 us).
__global__ __launch_bounds__(256) void k_scorep2c(
    const unsigned short* __restrict__ qs, const unsigned short* __restrict__ kk,
    const unsigned short* __restrict__ Pt, const int* __restrict__ rel,
    unsigned short* __restrict__ S)
{
  __shared__ unsigned short Ptl[32][512];      // 32 KB
  __shared__ unsigned short T[2][32][66];      // p2c exchange, double-buffered
  __shared__ unsigned short Tc[4][16][40];     // c2c exchange per wave (same-wave only)
  const int tid = threadIdx.x, l = tid & 63, w = tid >> 6;
  const int j0 = blockIdx.x * 32, z = blockIdx.y, ih = blockIdx.z;
  const long zb = (long)z << 20;
  const int lr = l & 15, lk = l >> 4;

  { // stage Pt rows (32 x 1KB, linear)
    const char* g = (const char*)(Pt + ((long)z * 1024 + j0) * 512);
    char* lb = (char*)&Ptl[0][0];
    #pragma unroll
    for (int it = 0; it < 8; it++)
      GLDS16(g + it * 4096 + w * 1024 + l * 16, lb + it * 4096 + w * 1024);
  }

  // k fragments: direct global->register, invariant across strips
  const unsigned short* kz = kk + (long)z * 131072;
  bf16x8 kf[4][2];
  #pragma unroll
  for (int kt = 0; kt < 4; kt++)
    #pragma unroll
    for (int ni = 0; ni < 2; ni++)
      kf[kt][ni] = *(const bf16x8*)&kz[(j0 + ni * 16 + lr) * 128 + kt * 32 + lk * 8];

  const int jb = w * 8;               // gather-phase j-rows for this wave
  const int il = tid >> 2;            // add-phase strip-local i (0..63)
  const int jq = (tid & 3) * 8;       // add-phase j-quarter
  const unsigned short* qz = qs + (long)z * 131072;
  const int* relb = rel + zb + (long)(j0 + jb) * 1024 + l;

  // prologue: prefetch strips 0 and 1
  int rv0[8], rv1[8]; bf16x8 af0[4], af1[4];
  {
    const int ia = ih * 512, ib2 = ia + 64;
    #pragma unroll
    for (int jj = 0; jj < 8; jj++) rv0[jj] = relb[jj * 1024 + ia];
    #pragma unroll
    for (int kt = 0; kt < 4; kt++)
      af0[kt] = *(const bf16x8*)&qz[(ia + w * 16 + lr) * 128 + kt * 32 + lk * 8];
    #pragma unroll
    for (int jj = 0; jj < 8; jj++) rv1[jj] = relb[jj * 1024 + ib2];
    #pragma unroll
    for (int kt = 0; kt < 4; kt++)
      af1[kt] = *(const bf16x8*)&qz[(ib2 + w * 16 + lr) * 128 + kt * 32 + lk * 8];
  }
  __syncthreads();   // Ptl staged (full drain here is fine: once per block)

  #pragma unroll
  for (int s = 0; s < 8; s++){
    const int i0 = ih * 512 + s * 64;
    const int tb = s & 1;
    // gather phase (uses strip-s prefetch rv0)
    unsigned short vals[8];
    #pragma unroll
    for (int jj = 0; jj < 8; jj++) vals[jj] = Ptl[jb + jj][rv0[jj] & 511];
    #pragma unroll
    for (int jj = 0; jj < 8; jj++) T[tb][jb + jj][l] = vals[jj];
    // prefetch strip s+2 (stays in flight across barriers)
    int rvn[8] = {}; bf16x8 afn[4] = {};
    if (s < 6){
      const int i2 = i0 + 128;
      #pragma unroll
      for (int jj = 0; jj < 8; jj++) rvn[jj] = relb[jj * 1024 + i2];
      #pragma unroll
      for (int kt = 0; kt < 4; kt++)
        afn[kt] = *(const bf16x8*)&qz[(i2 + w * 16 + lr) * 128 + kt * 32 + lk * 8];
    }
    asm volatile("s_waitcnt lgkmcnt(0)" ::: "memory");  // T writes visible; vmcnt untouched
    __builtin_amdgcn_s_barrier();
    __builtin_amdgcn_sched_barrier(0);                  // rule #18: pin ordering after raw barrier

    // compute phase: wave w computes strip rows w*16..w*16+16 x 32 j
    f32x4 acc0 = {}, acc1 = {};
    #pragma unroll
    for (int kt = 0; kt < 4; kt++){
      acc0 = __builtin_amdgcn_mfma_f32_16x16x32_bf16(af0[kt], kf[kt][0], acc0, 0, 0, 0);
      acc1 = __builtin_amdgcn_mfma_f32_16x16x32_bf16(af0[kt], kf[kt][1], acc1, 0, 0, 0);
    }
    #pragma unroll
    for (int r = 0; r < 4; r++){
      Tc[w][lk * 4 + r][lr]      = f2bf(acc0[r]);
      Tc[w][lk * 4 + r][16 + lr] = f2bf(acc1[r]);
    }
    // same-wave LDS dependency (compiler inserts lgkmcnt); T cross-wave covered by barrier
    float f[8];
    #pragma unroll
    for (int jj = 0; jj < 8; jj++)
      f[jj] = bf2f(Tc[w][l >> 2][jq + jj]) + bf2f(T[tb][jq + jj][il]);
    unsigned int aw[4];
    #pragma unroll
    for (int e = 0; e < 4; e++)
      aw[e] = (unsigned)f2bf(f[2*e]) | ((unsigned)f2bf(f[2*e+1]) << 16);
    *(uint4*)(S + zb + (long)(i0 + il) * 1024 + j0 + jq) = make_uint4(aw[0], aw[1], aw[2], aw[3]);

    // rotate prefetch registers (copy-propagated away by the full unroll)
    #pragma unroll
    for (int jj = 0; jj < 8; jj++){ rv0[jj] = rv1[jj]; rv1[jj] = rvn[jj]; }
    #pragma unroll
    for (int kt = 0; kt < 4; kt++){ af0[kt] = af1[kt]; af1[kt] = afn[kt]; }
  }
}

// ---------------- fused c2p + mask + exp + PV: oh = softmax_num(S + c2p) @ v / rowsum ----
// Block (ib in [0,32), z): 32 i-rows x 128 dk. K=1024 split ACROSS WAVES (wave w owns
// j in [256w, 256w+256)) -> A-prep is wave-private (no duplication), B-frags direct from
// global vT (L2-hot, no staging) -> ZERO barriers in the K-loop (round-8 lesson).
// Per 32-j step: S/rel/mask coalesced loads + c2p gather from LDS-staged Ccl + exp (f32)
// -> bf16 A-frags -> 16 MFMA. Tail: 4-phase f32 LDS reduction (acc + rowsum), then
// normalize + head remap. Numerics identical to the old c2pexp+PV pair.
__global__ __launch_bounds__(256) void k_pvfused(
    const unsigned short* __restrict__ S, const unsigned short* __restrict__ vT,
    const unsigned short* __restrict__ Cc, const int* __restrict__ rel,
    const int* __restrict__ maskp, unsigned short* __restrict__ oh)
{
  __shared__ unsigned short Ccl[32][512];   // 32 KB
  __shared__ float Racc[32][129];           // 16.5 KB; col 128 = row expsum
  const int tid = threadIdx.x, l = tid & 63, w = tid >> 6;
  const int ib = blockIdx.x, z = blockIdx.y;
  const long zb = (long)z << 20;
  const int i0 = ib * 32;
  const int lr = l & 15, lk = l >> 4;

  { // stage 32 Cc rows (32 KB)
    const char* g = (const char*)Cc + ((long)z * 1024 + i0) * 1024;
    char* lb = (char*)&Ccl[0][0];
    #pragma unroll
    for (int it = 0; it < 8; it++)
      GLDS16(g + it * 4096 + w * 1024 + l * 16, lb + it * 4096 + w * 1024);
  }
  __syncthreads();

  f32x4 acc[2][8] = {};
  float sacc[2] = {0.f, 0.f};
  const int jw0 = w * 256;
  const unsigned short* vz = vT + (long)z * 131072;

  for (int jt = 0; jt < 256; jt += 32){
    const int jw = jw0 + jt;
    bf16x8 af[2];
    #pragma unroll
    for (int mi = 0; mi < 2; mi++){
      const int row = i0 + mi * 16 + lr;
      const long base = zb + (long)row * 1024 + jw + lk * 8;
      uint4 aw = *(const uint4*)(S + base);
      int4 r0 = *(const int4*)(rel + base);
      int4 r1 = *(const int4*)(rel + base + 4);
      const long mbase = (((long)(z >> 3)) << 20) + (long)row * 1024 + jw + lk * 8;
      int4 m0 = *(const int4*)(maskp + mbase);
      int4 m1 = *(const int4*)(maskp + mbase + 4);
      unsigned int a4[4] = {aw.x, aw.y, aw.z, aw.w};
      const unsigned short* cl = &Ccl[mi * 16 + lr][0];
      float f[8];
      #pragma unroll
      for (int e = 0; e < 4; e++){
        f[2*e]   = bf2f((unsigned short)(a4[e] & 0xFFFFu));
        f[2*e+1] = bf2f((unsigned short)(a4[e] >> 16));
      }
      f[0] += bf2f(cl[r0.x & 511]); f[1] += bf2f(cl[r0.y & 511]);
      f[2] += bf2f(cl[r0.z & 511]); f[3] += bf2f(cl[r0.w & 511]);
      f[4] += bf2f(cl[r1.x & 511]); f[5] += bf2f(cl[r1.y & 511]);
      f[6] += bf2f(cl[r1.z & 511]); f[7] += bf2f(cl[r1.w & 511]);
      int mm[8] = {m0.x, m0.y, m0.z, m0.w, m1.x, m1.y, m1.z, m1.w};
      unsigned short o[8];
      #pragma unroll
      for (int e = 0; e < 8; e++){
        float p = (mm[e] == 1) ? 0.0f : __expf(f[e]);
        sacc[mi] += p;
        o[e] = f2bf(p);
      }
      af[mi] = *(const bf16x8*)o;
    }
    #pragma unroll
    for (int ni = 0; ni < 8; ni++){
      bf16x8 bfr = *(const bf16x8*)&vz[(ni * 16 + lr) * 1024 + jw + lk * 8];
      acc[0][ni] = __builtin_amdgcn_mfma_f32_16x16x32_bf16(af[0], bfr, acc[0][ni], 0, 0, 0);
      acc[1][ni] = __builtin_amdgcn_mfma_f32_16x16x32_bf16(af[1], bfr, acc[1][ni], 0, 0, 0);
    }
  }

  // row sums within wave: lane holds p for row mi*16+lr; reduce over lk groups
  #pragma unroll
  for (int mi = 0; mi < 2; mi++){
    sacc[mi] += __shfl_xor(sacc[mi], 16);
    sacc[mi] += __shfl_xor(sacc[mi], 32);
  }

  // 4-phase f32 reduction across waves (acc row = mi*16 + lk*4 + r, col = ni*16 + lr)
  #pragma unroll
  for (int ph = 0; ph < 4; ph++){
    if (w == ph){
      #pragma unroll
      for (int mi = 0; mi < 2; mi++){
        #pragma unroll
        for (int ni = 0; ni < 8; ni++)
          #pragma unroll
          for (int r = 0; r < 4; r++){
            float* p = &Racc[mi * 16 + lk * 4 + r][ni * 16 + lr];
            if (ph == 0) *p = acc[mi][ni][r]; else *p += acc[mi][ni][r];
          }
        if (lk == 0){
          float* ps = &Racc[mi * 16 + lr][128];
          if (ph == 0) *ps = sacc[mi]; else *ps += sacc[mi];
        }
      }
    }
    __syncthreads();
  }

  // epilogue: thread t -> row t>>3, 16 cols starting (t&7)*16; normalize + remap
  {
    const int row = tid >> 3, c0 = (tid & 7) * 16;
    const float inv = 1.0f / Racc[row][128];
    unsigned int ow[8];
    #pragma unroll
    for (int e = 0; e < 8; e++){
      float v0 = Racc[row][c0 + 2*e]     * inv;
      float v1 = Racc[row][c0 + 2*e + 1] * inv;
      ow[e] = (unsigned)f2bf(v0) | ((unsigned)f2bf(v1) << 16);
    }
    unsigned short* op = oh + ((long)(z >> 3) * 1024 + i0 + row) * 1024 + (z & 7) * 128 + c0;
    *(uint4*)op       = make_uint4(ow[0], ow[1], ow[2], ow[3]);
    *(uint4*)(op + 8) = make_uint4(ow[4], ow[5], ow[6], ow[7]);
  }
}

extern "C" void kernel_launch(void* const* d_in, const int* in_sizes, int n_in,
                              void* d_out, int out_size, void* d_ws, size_t ws_size,
                              hipStream_t stream){
  (void)in_sizes; (void)n_in; (void)out_size; (void)ws_size;
  const float* query = (const float*)d_in[0];
  const float* key_  = (const float*)d_in[1];
  const float* value = (const float*)d_in[2];
  const float* rele  = (const float*)d_in[3];
  const int*   rel   = (const int*)d_in[4];
  const int*   mask  = (const int*)d_in[5];
  const float* Wq = (const float*)d_in[6];  const float* bq = (const float*)d_in[7];
  const float* Wk = (const float*)d_in[8];  const float* bk = (const float*)d_in[9];
  const float* Wv = (const float*)d_in[10]; const float* bv = (const float*)d_in[11];
  const float* Wo = (const float*)d_in[12]; const float* bo = (const float*)d_in[13];
  const float* Wlq = (const float*)d_in[14]; const float* blq = (const float*)d_in[15];
  const float* Wlk = (const float*)d_in[16]; const float* blk = (const float*)d_in[17];
  const float* Wtq = (const float*)d_in[18]; const float* btq = (const float*)d_in[19];
  const float* Wtk = (const float*)d_in[20]; const float* btk = (const float*)d_in[21];

  char* ws = (char*)d_ws;
  auto U = [&](size_t off){ return (unsigned short*)(ws + off); };
  // region 0..64MB: score S; convert staging + small weights + biasPack (all dead
  // before the score write) alias into it
  unsigned short* S    = U(0);
  unsigned short* qf   = U(0);          // A for merged QKV proj (qf|kf|vf contiguous)
  unsigned short* lt   = U(25165824);   // rel_emb bf16: l then t
  unsigned short* WqT  = U(27262976);   // WqT|WkT|WvT contiguous
  unsigned short* WlqT = U(33554432);
  unsigned short* WlkT = U(34603008);
  unsigned short* WtqT = U(35651584);
  unsigned short* WtkT = U(36700160);
  float*  biasPack     = (float*)(ws + 38797312);  // 12 KB, inside S region (dead by score)
  unsigned short* WoT  = U(67108864);
  unsigned short* qs   = U(69206016);   // scaled q [B,H,N,DK]; qs|kk|vv contiguous
  unsigned short* kk   = U(77594624);
  unsigned short* vv   = U(85983232);
  unsigned short* oh   = U(85983232);   // out_heads aliases vv (vv dead after vtrans)
  unsigned short* vT   = U(94371840);   // v^T [B,H,DK,N]
  unsigned short* lqs  = U(102760448);  // scaled lq [H,L,DK]
  unsigned short* lks  = U(103809024);  // lk [H,L,DK]
  unsigned short* Pt   = U(104857600);  // p2c table [B,H,N(j),L(r)]
  unsigned short* Cc   = U(138412032);  // c2p table [B,H,N(i),L(l)]

  const float invs = 1.0f / sqrtf(384.0f);  // 1/sqrt(3*DK)
  dim3 b256(256), b644(64, 4);

  // merged converts + bias pack
  k_convert4<<<2048, b256, 0, stream>>>(query, key_, value, rele, (ushort4*)ws,
                                        bq, bk, bv, biasPack);

  // merged weight transposes
  WtArgs wa;
  wa.W[0]=Wq;  wa.Wd[0]=WqT;           wa.N[0]=1024;
  wa.W[1]=Wk;  wa.Wd[1]=U(29360128);   wa.N[1]=1024;
  wa.W[2]=Wv;  wa.Wd[2]=U(31457280);   wa.N[2]=1024;
  wa.W[3]=Wo;  wa.Wd[3]=WoT;           wa.N[3]=1024;
  wa.W[4]=Wlq; wa.Wd[4]=WlqT;          wa.N[4]=512;
  wa.W[5]=Wlk; wa.Wd[5]=WlkT;          wa.N[5]=512;
  wa.W[6]=Wtq; wa.Wd[6]=WtqT;          wa.N[6]=512;
  wa.W[7]=Wtk; wa.Wd[7]=WtkT;          wa.N[7]=512;
  k_wtrans8<<<dim3(16,16,8), b644, 0, stream>>>(wa);

  // merged q/k/v projections: M=12288 (scale folded into q covers /sqrt(384) of c2c,c2p)
  k_gemm<6><<<dim3(8,96,1), b256, 0, stream>>>(qf,0, WqT,0,0, qs, biasPack, invs,
                                               12288,1024,1024, 10,0);

  // merged rel projections (scale folded into lq covers /sqrt(384) of p2c)
  RelArgs ra;
  ra.A[0]=lt;        ra.B[0]=WlqT; ra.C[0]=lqs; ra.bias[0]=blq; ra.scale[0]=invs; ra.hb[0]=0;
  ra.A[1]=lt+524288; ra.B[1]=WtqT; ra.C[1]=lqs; ra.bias[1]=btq; ra.scale[1]=invs; ra.hb[1]=4;
  ra.A[2]=lt;        ra.B[2]=WlkT; ra.C[2]=lks; ra.bias[2]=blk; ra.scale[2]=1.0f; ra.hb[2]=0;
  ra.A[3]=lt+524288; ra.B[3]=WtkT; ra.C[3]=lks; ra.bias[3]=btk; ra.scale[3]=1.0f; ra.hb[3]=4;
  k_relproj<<<dim3(4,4,4), b256, 0, stream>>>(ra);

  k_vtrans<<<dim3(2,16,32), b644, 0, stream>>>(vv, vT);

  // tables: Pt[z][j][r] = k_j . lq_r ; Cc[z][i][l] = q_i . lk_l
  k_gemm<0><<<dim3(4,8,32), b256, 0, stream>>>(kk,131072, lqs,65536,7, Pt, nullptr,1.0f, 1024,512,128, 0,0);
  k_gemm<0><<<dim3(4,8,32), b256, 0, stream>>>(qs,131072, lks,65536,7, Cc, nullptr,1.0f, 1024,512,128, 0,0);

  // fused score: c2c MFMA + p2c gather -> S
  k_scorep2c<<<dim3(32,32,2), b256, 0, stream>>>(qs, kk, Pt, rel, S);

  // fused c2p + mask + exp + PV -> out_heads (kills the 128 MB S round-trip of c2pexp)
  k_pvfused<<<dim3(32,32), b256, 0, stream>>>(S, vT, Cc, rel, mask, oh);

  // final: d_out = out_heads @ Wo + bo   (f32 out; 64-row tiles -> 512 blocks = 2/CU)
  k_gemm64<2><<<dim3(8,64,1), b256, 0, stream>>>(oh,0, WoT,0,0, d_out, bo, 1.0f, 4096,1024,1024);
}